// Round 7
// baseline (729.737 us; speedup 1.0000x reference)
//
#include <hip/hip_runtime.h>
#include <cstddef>
#include <cstdint>

// Problem constants
#define B_   4
#define N_   2048
#define M_   576
#define C_   512
#define H_   8
#define KVH_ 2
#define D_   64
#define E_   8
#define F_   2048
#define BN_  (B_*N_)    // 8192 tokens
#define BM_  (B_*M_)    // 2304 vision tokens

typedef __attribute__((ext_vector_type(8))) short bf16x8;
typedef __attribute__((ext_vector_type(4))) float f32x4;

__device__ __forceinline__ unsigned short f2bf(float f) {
    union { float f; unsigned int u; } v; v.f = f;
    unsigned int r = v.u + 0x7FFFu + ((v.u >> 16) & 1u);
    return (unsigned short)(r >> 16);
}
__device__ __forceinline__ float bf2f(unsigned short u) {
    union { unsigned int u; float f; } v; v.u = ((unsigned int)u) << 16;
    return v.f;
}

// async global->LDS 16B/lane; LDS dest = wave-uniform base + lane*16
typedef __attribute__((address_space(1))) void glb_void;
typedef __attribute__((address_space(3))) void lds_void;
__device__ __forceinline__ void gl2lds16(const unsigned short* g, unsigned short* l) {
    __builtin_amdgcn_global_load_lds((glb_void*)g, (lds_void*)l, 16, 0, 0);
}

// ---------------------------------------------------------------------------
// prep_all: ALL weight transposes + vis cast + bias packs + ctrl zero in ONE
// launch. Block ranges are compile-time constants.
// ---------------------------------------------------------------------------
__global__ __launch_bounds__(256) void prep_all(
    const float* __restrict__ sa_wq, const float* __restrict__ sa_wk,
    const float* __restrict__ sa_wv, const float* __restrict__ sa_wo,
    const float* __restrict__ ca_wq, const float* __restrict__ ca_wk,
    const float* __restrict__ ca_wv, const float* __restrict__ ca_wo,
    const float* __restrict__ e_w1, const float* __restrict__ e_w2,
    const float* __restrict__ vis,
    const float* __restrict__ sa_bk, const float* __restrict__ sa_bv,
    const float* __restrict__ ca_bk, const float* __restrict__ ca_bv,
    unsigned short* __restrict__ sa_wqt, unsigned short* __restrict__ sa_wkvt,
    unsigned short* __restrict__ sa_wot,
    unsigned short* __restrict__ ca_wqt, unsigned short* __restrict__ ca_wkvt,
    unsigned short* __restrict__ ca_wot,
    unsigned short* __restrict__ w1t, unsigned short* __restrict__ w2t,
    unsigned short* __restrict__ visbf,
    float* __restrict__ bkv_sa, float* __restrict__ bkv_ca,
    int* __restrict__ ctrl)
{
    __shared__ float T[32][33];
    int t = blockIdx.x;
    int tid = threadIdx.x;

    if (t < 17664) {
        const float* W; unsigned short* Wt; int K, N, kt, nt;
        if (t < 1280) {
            if (t < 256)      { W = sa_wq; Wt = sa_wqt; K = 512; N = 512; int r = t;        nt = r & 15; kt = r >> 4; }
            else if (t < 320) { W = sa_wk; Wt = sa_wkvt;            K = 512; N = 128; int r = t - 256; nt = r & 3;  kt = r >> 2; }
            else if (t < 384) { W = sa_wv; Wt = sa_wkvt + 128*512;  K = 512; N = 128; int r = t - 320; nt = r & 3;  kt = r >> 2; }
            else if (t < 640) { W = sa_wo; Wt = sa_wot; K = 512; N = 512; int r = t - 384;  nt = r & 15; kt = r >> 4; }
            else if (t < 896) { W = ca_wq; Wt = ca_wqt; K = 512; N = 512; int r = t - 640;  nt = r & 15; kt = r >> 4; }
            else if (t < 960) { W = ca_wk; Wt = ca_wkvt;            K = 512; N = 128; int r = t - 896; nt = r & 3;  kt = r >> 2; }
            else if (t < 1024){ W = ca_wv; Wt = ca_wkvt + 128*512;  K = 512; N = 128; int r = t - 960; nt = r & 3;  kt = r >> 2; }
            else              { W = ca_wo; Wt = ca_wot; K = 512; N = 512; int r = t - 1024; nt = r & 15; kt = r >> 4; }
        } else if (t < 9472) {
            int r = t - 1280; int e = r >> 10; r &= 1023;
            W = e_w1 + (size_t)e * C_ * F_; Wt = w1t + (size_t)e * C_ * F_;
            K = C_; N = F_; nt = r & 63; kt = r >> 6;
        } else {
            int r = t - 9472; int e = r >> 10; r &= 1023;
            W = e_w2 + (size_t)e * F_ * C_; Wt = w2t + (size_t)e * F_ * C_;
            K = F_; N = C_; nt = r & 15; kt = r >> 4;
        }
        int rr = tid >> 3, c4 = (tid & 7) * 4;
        int k0 = kt * 32, n0 = nt * 32;
        float4 v = *(const float4*)&W[(size_t)(k0 + rr) * N + n0 + c4];
        T[rr][c4 + 0] = v.x; T[rr][c4 + 1] = v.y; T[rr][c4 + 2] = v.z; T[rr][c4 + 3] = v.w;
        __syncthreads();
        ushort4 o;
        o.x = f2bf(T[c4 + 0][rr]); o.y = f2bf(T[c4 + 1][rr]);
        o.z = f2bf(T[c4 + 2][rr]); o.w = f2bf(T[c4 + 3][rr]);
        *(ushort4*)&Wt[(size_t)(n0 + rr) * K + k0 + c4] = o;
    } else if (t < 18816) {
        int i = (t - 17664) * 1024 + tid * 4;
        float4 v = *(const float4*)(vis + i);
        ushort4 o;
        o.x = f2bf(v.x); o.y = f2bf(v.y); o.z = f2bf(v.z); o.w = f2bf(v.w);
        *(ushort4*)(visbf + i) = o;
    } else {
        if (tid < 128) {
            bkv_sa[tid]       = sa_bk[tid];
            bkv_sa[128 + tid] = sa_bv[tid];
            bkv_ca[tid]       = ca_bk[tid];
            bkv_ca[128 + tid] = ca_bv[tid];
        }
        if (tid < 32) ctrl[tid] = 0;
    }
}

// ---------------------------------------------------------------------------
// LayerNorm bf16 out (LN1/LN2)
// ---------------------------------------------------------------------------
__global__ __launch_bounds__(256) void ln_bf(const float* __restrict__ x,
    const float* __restrict__ g, const float* __restrict__ b, unsigned short* __restrict__ out)
{
    int row = blockIdx.x;
    const float* xr = x + (size_t)row * C_;
    float s = 0.f, ss = 0.f;
    for (int c = threadIdx.x; c < C_; c += 256) { float v = xr[c]; s += v; ss += v * v; }
    __shared__ float S1[256], S2[256];
    S1[threadIdx.x] = s; S2[threadIdx.x] = ss;
    __syncthreads();
    for (int o = 128; o > 0; o >>= 1) {
        if (threadIdx.x < o) { S1[threadIdx.x] += S1[threadIdx.x + o]; S2[threadIdx.x] += S2[threadIdx.x + o]; }
        __syncthreads();
    }
    float mu  = S1[0] * (1.f / C_);
    float var = S2[0] * (1.f / C_) - mu * mu;
    float inv = rsqrtf(var + 1e-6f);
    unsigned short* orow = out + (size_t)row * C_;
    for (int c = threadIdx.x; c < C_; c += 256)
        orow[c] = f2bf((xr[c] - mu) * inv * g[c] + b[c]);
}

// LayerNorm dual out: fp32 (router, bit-identical routing) + bf16 (GEMM input)
__global__ __launch_bounds__(256) void ln_dual(const float* __restrict__ x,
    const float* __restrict__ g, const float* __restrict__ b,
    float* __restrict__ outF, unsigned short* __restrict__ outBf)
{
    int row = blockIdx.x;
    const float* xr = x + (size_t)row * C_;
    float s = 0.f, ss = 0.f;
    for (int c = threadIdx.x; c < C_; c += 256) { float v = xr[c]; s += v; ss += v * v; }
    __shared__ float S1[256], S2[256];
    S1[threadIdx.x] = s; S2[threadIdx.x] = ss;
    __syncthreads();
    for (int o = 128; o > 0; o >>= 1) {
        if (threadIdx.x < o) { S1[threadIdx.x] += S1[threadIdx.x + o]; S2[threadIdx.x] += S2[threadIdx.x + o]; }
        __syncthreads();
    }
    float mu  = S1[0] * (1.f / C_);
    float var = S2[0] * (1.f / C_) - mu * mu;
    float inv = rsqrtf(var + 1e-6f);
    for (int c = threadIdx.x; c < C_; c += 256) {
        float v = (xr[c] - mu) * inv * g[c] + b[c];
        outF[(size_t)row * C_ + c] = v;
        outBf[(size_t)row * C_ + c] = f2bf(v);
    }
}

// ---------------------------------------------------------------------------
// Dense bf16 MFMA GEMM (async staging, XOR-swizzled unpadded LDS).
// out = A[M][K] @ Bt[N][K]^T + bias. 128x128 tile, 4 waves 2x2 of 64x64.
// mode 0: bf16 out[M][N]; mode 1: fp32 out[M][N] +=; mode 4: out = xin + acc+bias
// mode 3: fused KV: cols<128 -> K natural [rows][128]; cols>=128 -> V
//         transposed per batch: outBf2[(b*128+(gc-128))*NkPer + m]
// ---------------------------------------------------------------------------
__global__ __launch_bounds__(256) void dense_mfma(
    const unsigned short* __restrict__ Abf,
    const unsigned short* __restrict__ Btbf,
    const float* __restrict__ bias,
    const float* __restrict__ xin,
    float* __restrict__ outF,
    unsigned short* __restrict__ outBf,
    unsigned short* __restrict__ outBf2,
    int N, int K, int mode, int NkPer)
{
    int row0 = blockIdx.y * 128;
    int col0 = blockIdx.x * 128;

    __shared__ unsigned short As[128 * 32];   // 64B rows, swizzled chunks
    __shared__ unsigned short Bs[128 * 32];

    int tid = threadIdx.x;
    int lane = tid & 63, wid = tid >> 6;
    int lrow = lane >> 2;
    int cswz = (((lane & 3) ^ ((lane >> 3) & 3)) << 3);   // shorts
    int ar0 = 16 * (wid * 2) + lrow;
    int ar1 = ar0 + 16;
    const unsigned short* gA0 = Abf + (size_t)(row0 + ar0) * K + cswz;
    const unsigned short* gA1 = Abf + (size_t)(row0 + ar1) * K + cswz;
    const unsigned short* gB0 = Btbf + (size_t)(col0 + ar0) * K + cswz;
    const unsigned short* gB1 = Btbf + (size_t)(col0 + ar1) * K + cswz;
    unsigned short* lA0 = As + (wid * 2) * 512;
    unsigned short* lA1 = lA0 + 512;
    unsigned short* lB0 = Bs + (wid * 2) * 512;
    unsigned short* lB1 = lB0 + 512;

    int wm0 = (wid & 1) * 64, wn0 = (wid >> 1) * 64;
    int lm = lane & 15, lq = lane >> 4;
    int swb = (lq ^ ((lm >> 1) & 3)) << 3;    // shorts
    int aoff[4], boff[4];
#pragma unroll
    for (int i = 0; i < 4; i++) {
        aoff[i] = (wm0 + 16 * i + lm) * 32 + swb;
        boff[i] = (wn0 + 16 * i + lm) * 32 + swb;
    }

    f32x4 acc[4][4];
#pragma unroll
    for (int i = 0; i < 4; i++)
#pragma unroll
        for (int j = 0; j < 4; j++)
            acc[i][j] = (f32x4){0.f, 0.f, 0.f, 0.f};

    for (int k0 = 0; k0 < K; k0 += 32) {
        __syncthreads();
        gl2lds16(gA0 + k0, lA0);
        gl2lds16(gA1 + k0, lA1);
        gl2lds16(gB0 + k0, lB0);
        gl2lds16(gB1 + k0, lB1);
        __syncthreads();

        bf16x8 av[4], bv[4];
#pragma unroll
        for (int i = 0; i < 4; i++) av[i] = *(const bf16x8*)&As[aoff[i]];
#pragma unroll
        for (int i = 0; i < 4; i++) bv[i] = *(const bf16x8*)&Bs[boff[i]];
#pragma unroll
        for (int mi = 0; mi < 4; mi++)
#pragma unroll
            for (int ni = 0; ni < 4; ni++)
                acc[mi][ni] = __builtin_amdgcn_mfma_f32_16x16x32_bf16(av[mi], bv[ni], acc[mi][ni], 0, 0, 0);
    }

#pragma unroll
    for (int mi = 0; mi < 4; mi++) {
#pragma unroll
        for (int ri = 0; ri < 4; ri++) {
            int gr = row0 + wm0 + 16 * mi + lq * 4 + ri;
            if (mode == 3) {
#pragma unroll
                for (int ni = 0; ni < 4; ni++) {
                    int gc = col0 + wn0 + 16 * ni + lm;
                    float v = acc[mi][ni][ri] + bias[gc];
                    if (gc < 128) {
                        outBf[(size_t)gr * 128 + gc] = f2bf(v);
                    } else {
                        int bb = gr / NkPer;
                        int mm = gr - bb * NkPer;
                        outBf2[((size_t)bb * 128 + (gc - 128)) * NkPer + mm] = f2bf(v);
                    }
                }
            } else if (mode == 1) {
                size_t orow = (size_t)gr * N;
#pragma unroll
                for (int ni = 0; ni < 4; ni++) {
                    int gc = col0 + wn0 + 16 * ni + lm;
                    outF[orow + gc] += acc[mi][ni][ri] + bias[gc];
                }
            } else if (mode == 4) {
                size_t orow = (size_t)gr * N;
#pragma unroll
                for (int ni = 0; ni < 4; ni++) {
                    int gc = col0 + wn0 + 16 * ni + lm;
                    outF[orow + gc] = xin[orow + gc] + acc[mi][ni][ri] + bias[gc];
                }
            } else {
                size_t orow = (size_t)gr * N;
#pragma unroll
                for (int ni = 0; ni < 4; ni++) {
                    int gc = col0 + wn0 + 16 * ni + lm;
                    outBf[orow + gc] = f2bf(acc[mi][ni][ri] + bias[gc]);
                }
            }
        }
    }
}

// ---------------------------------------------------------------------------
// MFMA flash attention (fixed-shift softmax, split-K capable) — validated r5/r6
// ---------------------------------------------------------------------------
__global__ __launch_bounds__(256) void attn_mfma(
    const unsigned short* __restrict__ Q,
    const unsigned short* __restrict__ K,
    const unsigned short* __restrict__ Vt,
    unsigned short* __restrict__ Obf,
    float* __restrict__ Opart,
    float* __restrict__ Lpart,
    int NkPer, int causal)
{
    __shared__ unsigned short Qs[64 * 72];
    __shared__ unsigned short Ks[64 * 72];
    __shared__ unsigned short Vs[64 * 72];
    unsigned short* Ps = Qs;

    int tid = threadIdx.x;
    int qt = blockIdx.x, bh = blockIdx.y, z = blockIdx.z;
    int b = bh >> 3, h = bh & 7, g = h >> 2;
    int q0 = qt * 64;

#pragma unroll
    for (int i = 0; i < 2; i++) {
        int s = tid + (i << 8);
        int r = s >> 3, c8 = (s & 7) << 3;
        *(uint4*)&Qs[r * 72 + c8] =
            *(const uint4*)&Q[(size_t)(b * N_ + q0 + r) * C_ + h * D_ + c8];
    }
    __syncthreads();

    int lane = tid & 63, wid = tid >> 6;
    int lm = lane & 15, lq = lane >> 4;
    int arow = wid * 16 + lm;

    bf16x8 qf[2];
    qf[0] = *(const bf16x8*)&Qs[arow * 72 + lq * 8];
    qf[1] = *(const bf16x8*)&Qs[arow * 72 + lq * 8 + 32];

    float lsum[4];
    f32x4 of[4];
#pragma unroll
    for (int i = 0; i < 4; i++) { lsum[i] = 0.f; of[i] = (f32x4){0.f,0.f,0.f,0.f}; }

    int nkt = causal ? (qt + 1) : ((NkPer + 63) >> 6);
    int nz = gridDim.z;
    int per = (nkt + nz - 1) / nz;
    int kt0 = z * per;
    int kt1 = min(nkt, kt0 + per);

    for (int kt = kt0; kt < kt1; kt++) {
        int k0 = kt << 6;
        __syncthreads();
#pragma unroll
        for (int i = 0; i < 2; i++) {
            int s = tid + (i << 8);
            int r = s >> 3, c8 = (s & 7) << 3;
            *(uint4*)&Ks[r * 72 + c8] =
                *(const uint4*)&K[(size_t)(b * NkPer + k0 + r) * (KVH_ * D_) + g * D_ + c8];
            *(uint4*)&Vs[r * 72 + c8] =
                *(const uint4*)&Vt[(size_t)(b * (KVH_ * D_) + g * D_ + r) * NkPer + k0 + c8];
        }
        __syncthreads();

        f32x4 sf[4];
#pragma unroll
        for (int i = 0; i < 4; i++) sf[i] = (f32x4){0.f,0.f,0.f,0.f};
#pragma unroll
        for (int ks = 0; ks < 2; ks++) {
#pragma unroll
            for (int ni = 0; ni < 4; ni++) {
                bf16x8 bv = *(const bf16x8*)&Ks[(16 * ni + lm) * 72 + lq * 8 + 32 * ks];
                sf[ni] = __builtin_amdgcn_mfma_f32_16x16x32_bf16(qf[ks], bv, sf[ni], 0, 0, 0);
            }
        }

        bool diag = causal && (k0 + 63 > q0 + wid * 16);
#pragma unroll
        for (int ni = 0; ni < 4; ni++)
#pragma unroll
            for (int ri = 0; ri < 4; ri++) {
                float v = sf[ni][ri] * 0.125f - 8.f;
                if (diag && (k0 + 16 * ni + lm > q0 + wid * 16 + lq * 4 + ri)) v = -1e30f;
                float p = __expf(v);
                sf[ni][ri] = p;
                lsum[ri] += p;
            }

#pragma unroll
        for (int ni = 0; ni < 4; ni++)
#pragma unroll
            for (int ri = 0; ri < 4; ri++)
                Ps[(wid * 16 + lq * 4 + ri) * 72 + 16 * ni + lm] = f2bf(sf[ni][ri]);
        __syncthreads();

        bf16x8 pf0 = *(const bf16x8*)&Ps[arow * 72 + lq * 8];
        bf16x8 pf1 = *(const bf16x8*)&Ps[arow * 72 + lq * 8 + 32];
#pragma unroll
        for (int ni = 0; ni < 4; ni++) {
            bf16x8 vv0 = *(const bf16x8*)&Vs[(16 * ni + lm) * 72 + lq * 8];
            bf16x8 vv1 = *(const bf16x8*)&Vs[(16 * ni + lm) * 72 + lq * 8 + 32];
            of[ni] = __builtin_amdgcn_mfma_f32_16x16x32_bf16(pf0, vv0, of[ni], 0, 0, 0);
            of[ni] = __builtin_amdgcn_mfma_f32_16x16x32_bf16(pf1, vv1, of[ni], 0, 0, 0);
        }
    }

#pragma unroll
    for (int ri = 0; ri < 4; ri++) {
        float s = lsum[ri];
        s += __shfl_xor(s, 1);
        s += __shfl_xor(s, 2);
        s += __shfl_xor(s, 4);
        s += __shfl_xor(s, 8);
        lsum[ri] = s;
    }

    if (nz == 1) {
#pragma unroll
        for (int ri = 0; ri < 4; ri++) {
            float inv = 1.f / lsum[ri];
            int q = q0 + wid * 16 + lq * 4 + ri;
            size_t orow = (size_t)(b * N_ + q) * C_ + h * D_;
#pragma unroll
            for (int ni = 0; ni < 4; ni++)
                Obf[orow + 16 * ni + lm] = f2bf(of[ni][ri] * inv);
        }
    } else {
        size_t zofs = (size_t)z * BN_ * C_;
#pragma unroll
        for (int ri = 0; ri < 4; ri++) {
            int q = q0 + wid * 16 + lq * 4 + ri;
            size_t orow = zofs + (size_t)(b * N_ + q) * C_ + h * D_;
#pragma unroll
            for (int ni = 0; ni < 4; ni++)
                Opart[orow + 16 * ni + lm] = of[ni][ri];
            if (lm == 0)
                Lpart[(size_t)z * (B_ * H_ * N_) + bh * N_ + q] = lsum[ri];
        }
    }
}

__global__ __launch_bounds__(256) void attn_combine(const float* __restrict__ Opart,
    const float* __restrict__ Lpart, unsigned short* __restrict__ Obf)
{
    int flat = (blockIdx.x * 256 + threadIdx.x) * 4;
    int row = flat >> 9, col = flat & 511;
    int b = row >> 11, q = row & (N_ - 1), h = col >> 6;
    int bh = b * 8 + h;
    float l = Lpart[bh * N_ + q] + Lpart[B_ * H_ * N_ + bh * N_ + q];
    float inv = 1.f / l;
    float4 o0 = *(const float4*)&Opart[flat];
    float4 o1 = *(const float4*)&Opart[(size_t)BN_ * C_ + flat];
    ushort4 o;
    o.x = f2bf((o0.x + o1.x) * inv); o.y = f2bf((o0.y + o1.y) * inv);
    o.z = f2bf((o0.z + o1.z) * inv); o.w = f2bf((o0.w + o1.w) * inv);
    *(ushort4*)&Obf[flat] = o;
}

// ---------------------------------------------------------------------------
// Router (atomic-free logits + reduce + aggregated scatter w/ slot record)
// ---------------------------------------------------------------------------
__global__ __launch_bounds__(256) void router_logits(const float* __restrict__ X,
    const float* __restrict__ RW, const float* __restrict__ RB,
    float* __restrict__ gprobs, int* __restrict__ topi, float* __restrict__ gatesv)
{
    int lane = threadIdx.x & 63;
    int t = blockIdx.x * 4 + (threadIdx.x >> 6);
    const float* xr = X + (size_t)t * C_;
    float p[8] = {};
    for (int i = 0; i < 8; i++) {
        int c = i * 64 + lane;
        float xv = xr[c];
#pragma unroll
        for (int e = 0; e < 8; e++) p[e] = fmaf(xv, RW[c * 8 + e], p[e]);
    }
#pragma unroll
    for (int e = 0; e < 8; e++) {
        float v = p[e];
        v += __shfl_xor(v, 32, 64);
        v += __shfl_xor(v, 16, 64);
        v += __shfl_xor(v, 8, 64);
        v += __shfl_xor(v, 4, 64);
        v += __shfl_xor(v, 2, 64);
        v += __shfl_xor(v, 1, 64);
        p[e] = v;
    }
    if (lane == 0) {
        float logits[8], mx = -1e30f;
        for (int e = 0; e < 8; e++) { logits[e] = p[e] + RB[e]; mx = fmaxf(mx, logits[e]); }
        float pr[8], sum = 0.f;
        for (int e = 0; e < 8; e++) { pr[e] = expf(logits[e] - mx); sum += pr[e]; }
        float inv = 1.f / sum;
        for (int e = 0; e < 8; e++) { pr[e] *= inv; gprobs[t * 8 + e] = pr[e]; }
        int i1 = 0;
        for (int e = 1; e < 8; e++) if (pr[e] > pr[i1]) i1 = e;
        int i2 = (i1 == 0) ? 1 : 0;
        for (int e = 0; e < 8; e++) if (e != i1 && pr[e] > pr[i2]) i2 = e;
        float v1 = pr[i1], v2 = pr[i2], sg = 1.f / (v1 + v2);
        topi[t * 2]     = i1;  topi[t * 2 + 1]   = i2;
        gatesv[t * 2]   = v1 * sg;  gatesv[t * 2 + 1] = v2 * sg;
    }
}

__global__ __launch_bounds__(256) void router_reduce(const float* __restrict__ gprobs,
    const int* __restrict__ topi, int* __restrict__ ctrl, float* __restrict__ psum)
{
    __shared__ float fs[256];
    __shared__ int   is_[256];
    int bid = blockIdx.x, tid = threadIdx.x;
    if (bid < 8) {
        float s = 0.f;
        for (int t = tid; t < BN_; t += 256) s += gprobs[t * 8 + bid];
        fs[tid] = s; __syncthreads();
        for (int o = 128; o > 0; o >>= 1) { if (tid < o) fs[tid] += fs[tid + o]; __syncthreads(); }
        if (tid == 0) psum[bid] = fs[0];
    } else {
        int e = bid - 8, c = 0;
        for (int i = tid; i < BN_ * 2; i += 256) c += (topi[i] == e);
        is_[tid] = c; __syncthreads();
        for (int o = 128; o > 0; o >>= 1) { if (tid < o) is_[tid] += is_[tid + o]; __syncthreads(); }
        if (tid == 0) ctrl[e] = is_[0];
    }
}

__global__ void router_offsets(int* __restrict__ ctrl)
{
    if (threadIdx.x == 0 && blockIdx.x == 0) {
        int off = 0;
        for (int e = 0; e < 8; e++) {
            ctrl[16 + e] = off;
            off += (ctrl[e] + 127) & ~127;
        }
        ctrl[24] = off;
    }
}

__global__ __launch_bounds__(256) void router_scatter(const int* __restrict__ topi,
    const float* __restrict__ gatesv, int* __restrict__ rowtok,
    int* __restrict__ slotidx, int* __restrict__ ctrl)
{
    __shared__ int lcnt[8];
    __shared__ int lbase[8];
    int tid = threadIdx.x;
    int t = blockIdx.x * 256 + tid;
    if (tid < 8) lcnt[tid] = 0;
    __syncthreads();
    int e0 = topi[t * 2], e1 = topi[t * 2 + 1];
    int p0 = atomicAdd(&lcnt[e0], 1);
    int p1 = atomicAdd(&lcnt[e1], 1);
    __syncthreads();
    if (tid < 8) lbase[tid] = atomicAdd(&ctrl[8 + tid], lcnt[tid]);
    __syncthreads();
    int s0 = ctrl[16 + e0] + lbase[e0] + p0;
    int s1 = ctrl[16 + e1] + lbase[e1] + p1;
    rowtok[s0] = t;
    rowtok[s1] = t;
    slotidx[t * 2]     = s0;
    slotidx[t * 2 + 1] = s1;
}

// ---------------------------------------------------------------------------
// MoE bf16 MFMA GEMM: async staging + LDS-staged vectorized epilogue.
// Grid: x = row-block (fastest -> weight-tile L2 reuse), y = col-block, z = e.
// mode 1: A = Xbf gathered by rowtok; out = gelu(acc+b1) -> bf16 [slot][F]
// mode 2: A = Hbuf rows off+...;      out = acc+b2       -> bf16 [slot][C]
// ---------------------------------------------------------------------------
__global__ __launch_bounds__(256) void moe_mfma(
    const unsigned short* __restrict__ Abf,
    const unsigned short* __restrict__ Btbf,
    const float* __restrict__ biasAll,
    unsigned short* __restrict__ outBf,
    const int* __restrict__ rowtok,
    const int* __restrict__ ctrl,
    int N, int K, int mode)
{
    int e = blockIdx.z;
    int cnt = ctrl[e];
    int row0 = blockIdx.x * 128;       // x = row-block (fastest varying)
    if (row0 >= cnt) return;
    int off = ctrl[16 + e];
    int col0 = blockIdx.y * 128;
    const unsigned short* Bt = Btbf + (size_t)e * N * K;
    const float* bias = biasAll + (size_t)e * N;

    __shared__ unsigned short As[128 * 32];
    __shared__ unsigned short Bs[128 * 32];
    __shared__ __align__(16) unsigned short Cs[4][32 * 72];   // per-wave epilogue stage
    __shared__ int toks[128];

    int tid = threadIdx.x;
    if (mode == 1 && tid < 128) {
        int gl = row0 + tid;
        toks[tid] = rowtok[off + (gl < cnt ? gl : 0)];
    }
    __syncthreads();

    int lane = tid & 63, wid = tid >> 6;
    int lrow = lane >> 2;
    int cswz = (((lane & 3) ^ ((lane >> 3) & 3)) << 3);
    int ar0 = 16 * (wid * 2) + lrow;
    int ar1 = ar0 + 16;
    const unsigned short *gA0, *gA1;
    if (mode == 1) {
        gA0 = Abf + (size_t)toks[ar0] * K + cswz;
        gA1 = Abf + (size_t)toks[ar1] * K + cswz;
    } else {
        gA0 = Abf + (size_t)(off + row0 + ar0) * K + cswz;
        gA1 = Abf + (size_t)(off + row0 + ar1) * K + cswz;
    }
    const unsigned short* gB0 = Bt + (size_t)(col0 + ar0) * K + cswz;
    const unsigned short* gB1 = Bt + (size_t)(col0 + ar1) * K + cswz;
    unsigned short* lA0 = As + (wid * 2) * 512;
    unsigned short* lA1 = lA0 + 512;
    unsigned short* lB0 = Bs + (wid * 2) * 512;
    unsigned short* lB1 = lB0 + 512;

    int wm0 = (wid & 1) * 64, wn0 = (wid >> 1) * 64;
    int lm = lane & 15, lq = lane >> 4;
    int swb = (lq ^ ((lm >> 1) & 3)) << 3;
    int aoff[4], boff[4];
#pragma unroll
    for (int i = 0; i < 4; i++) {
        aoff[i] = (wm0 + 16 * i + lm) * 32 + swb;
        boff[i] = (wn0 + 16 * i + lm) * 32 + swb;
    }

    f32x4 acc[4][4];
#pragma unroll
    for (int i = 0; i < 4; i++)
#pragma unroll
        for (int j = 0; j < 4; j++)
            acc[i][j] = (f32x4){0.f, 0.f, 0.f, 0.f};

    for (int k0 = 0; k0 < K; k0 += 32) {
        __syncthreads();
        gl2lds16(gA0 + k0, lA0);
        gl2lds16(gA1 + k0, lA1);
        gl2lds16(gB0 + k0, lB0);
        gl2lds16(gB1 + k0, lB1);
        __syncthreads();

        bf16x8 av[4], bv[4];
#pragma unroll
        for (int i = 0; i < 4; i++) av[i] = *(const bf16x8*)&As[aoff[i]];
#pragma unroll
        for (int i = 0; i < 4; i++) bv[i] = *(const bf16x8*)&Bs[boff[i]];
#pragma unroll
        for (int mi = 0; mi < 4; mi++)
#pragma unroll
            for (int ni = 0; ni < 4; ni++)
                acc[mi][ni] = __builtin_amdgcn_mfma_f32_16x16x32_bf16(av[mi], bv[ni], acc[mi][ni], 0, 0, 0);
    }

    // epilogue: wave-private LDS stage (32 rows/pass), vectorized global stores
    unsigned short* cs = Cs[wid];
#pragma unroll
    for (int p = 0; p < 2; p++) {
#pragma unroll
        for (int m2 = 0; m2 < 2; m2++) {
            int mi = 2 * p + m2;
#pragma unroll
            for (int ri = 0; ri < 4; ri++) {
                int gl = row0 + wm0 + 16 * mi + lq * 4 + ri;
                bool valid = gl < cnt;
#pragma unroll
                for (int ni = 0; ni < 4; ni++) {
                    int gc = col0 + wn0 + 16 * ni + lm;
                    float xv = acc[mi][ni][ri] + bias[gc];
                    float hv;
                    if (mode == 1) {
                        float z = 0.7978845608f * xv * fmaf(0.044715f, xv * xv, 1.f);
                        hv = valid ? __fdividef(xv, 1.f + __expf(-2.f * z)) : 0.f;
                    } else {
                        hv = xv;
                    }
                    cs[(m2 * 16 + lq * 4 + ri) * 72 + 16 * ni + lm] = f2bf(hv);
                }
            }
        }
        // wave-private readback (in-order within wave; compiler inserts lgkmcnt)
        int rr = lane >> 1;
        int ch = (lane & 1) * 32;
        int gl2 = row0 + wm0 + 32 * p + rr;
        size_t orow = (size_t)(off + gl2) * N + col0 + wn0 + ch;
        const unsigned short* rsrc = &cs[rr * 72 + ch];
#pragma unroll
        for (int j = 0; j < 4; j++)
            *(uint4*)&outBf[orow + j * 8] = *(const uint4*)&rsrc[j * 8];
    }
}

// combine: out[t][c] += g0*eo[s0][c] + g1*eo[s1][c]
__global__ __launch_bounds__(256) void moe_combine(const unsigned short* __restrict__ slots,
    const int* __restrict__ slotidx, const float* __restrict__ gatesv,
    float* __restrict__ out)
{
    int flat = (blockIdx.x * 256 + threadIdx.x) * 4;
    int t = flat >> 9, c = flat & 511;
    int s0 = slotidx[t * 2], s1 = slotidx[t * 2 + 1];
    float g0 = gatesv[t * 2], g1 = gatesv[t * 2 + 1];
    ushort4 a = *(const ushort4*)&slots[(size_t)s0 * C_ + c];
    ushort4 b = *(const ushort4*)&slots[(size_t)s1 * C_ + c];
    float4 o = *(float4*)&out[flat];
    o.x += g0 * bf2f(a.x) + g1 * bf2f(b.x);
    o.y += g0 * bf2f(a.y) + g1 * bf2f(b.y);
    o.z += g0 * bf2f(a.z) + g1 * bf2f(b.z);
    o.w += g0 * bf2f(a.w) + g1 * bf2f(b.w);
    *(float4*)&out[flat] = o;
}

// aux = E * sum_e (counts[e]/BN) * (psum[e]/BN)
__global__ void aux_kernel(const int* __restrict__ ctrl, const float* __restrict__ psum,
                           float* __restrict__ outaux)
{
    if (threadIdx.x == 0 && blockIdx.x == 0) {
        float s = 0.f;
        for (int e = 0; e < 8; e++)
            s += ((float)ctrl[e] / (float)BN_) * (psum[e] / (float)BN_);
        outaux[0] = 8.f * s;
    }
}

// ---------------------------------------------------------------------------
extern "C" void kernel_launch(void* const* d_in, const int* in_sizes, int n_in,
                              void* d_out, int out_size, void* d_ws, size_t ws_size,
                              hipStream_t stream)
{
    const float* x      = (const float*)d_in[0];
    const float* vis    = (const float*)d_in[1];
    const float* ln1g   = (const float*)d_in[2];
    const float* ln1b   = (const float*)d_in[3];
    const float* ln2g   = (const float*)d_in[4];
    const float* ln2b   = (const float*)d_in[5];
    const float* ln3g   = (const float*)d_in[6];
    const float* ln3b   = (const float*)d_in[7];
    const float* sa_wq  = (const float*)d_in[8];
    const float* sa_bq  = (const float*)d_in[9];
    const float* sa_wk  = (const float*)d_in[10];
    const float* sa_bk  = (const float*)d_in[11];
    const float* sa_wv  = (const float*)d_in[12];
    const float* sa_bv  = (const float*)d_in[13];
    const float* sa_wo  = (const float*)d_in[14];
    const float* sa_bo  = (const float*)d_in[15];
    const float* ca_wq  = (const float*)d_in[16];
    const float* ca_bq  = (const float*)d_in[17];
    const float* ca_wk  = (const float*)d_in[18];
    const float* ca_bk  = (const float*)d_in[19];
    const float* ca_wv  = (const float*)d_in[20];
    const float* ca_bv  = (const float*)d_in[21];
    const float* ca_wo  = (const float*)d_in[22];
    const float* ca_bo  = (const float*)d_in[23];
    const float* rw     = (const float*)d_in[24];
    const float* rb     = (const float*)d_in[25];
    const float* e_w1   = (const float*)d_in[26];
    const float* e_b1   = (const float*)d_in[27];
    const float* e_w2   = (const float*)d_in[28];
    const float* e_b2   = (const float*)d_in[29];

    float* out = (float*)d_out;

    char* ws = (char*)d_ws;
    size_t off = 0;
    auto alloc = [&](size_t bytes) -> void* {
        void* p = ws + off;
        off = (off + bytes + 255) & ~(size_t)255;
        return p;
    };
    float* hbuf    = (float*)alloc((size_t)BN_ * C_ * 4);                   // LN3 fp32
    unsigned short* hbz = (unsigned short*)alloc((size_t)BN_ * C_ * 2);     // bf16 LN out
    unsigned short* visbf = (unsigned short*)alloc((size_t)BM_ * C_ * 2);
    // eoslots (bf16 [17408][C] = 17.9 MB) overlays hbuf+hbz (25.2 MB), both
    // dead during MoE GEMM2/combine.
    unsigned short* eoslots = (unsigned short*)hbuf;
    // union region: attention temps overlap MoE H buffer (71.3 MB)
    char* ureg = (char*)alloc((size_t)17408 * F_ * 2);
    unsigned short* moeH = (unsigned short*)ureg;
    unsigned short* qbf  = (unsigned short*)(ureg);                          // 8.4 MB
    unsigned short* obf  = (unsigned short*)(ureg + (size_t)BN_ * C_ * 2);   // 8.4 MB
    unsigned short* kbf  = (unsigned short*)(ureg + (size_t)BN_ * C_ * 4);   // 2.1 MB
    unsigned short* vtbf = (unsigned short*)(ureg + (size_t)BN_ * C_ * 4 + (size_t)BN_ * KVH_ * D_ * 2);
    float* opart = (float*)(ureg + (size_t)BN_ * C_ * 4 + (size_t)BN_ * KVH_ * D_ * 4); // 2 x 16.8 MB
    float* lpart = (float*)(ureg + (size_t)BN_ * C_ * 4 + (size_t)BN_ * KVH_ * D_ * 4
                                 + (size_t)2 * BN_ * C_ * 4);
    unsigned short* sa_wqt = (unsigned short*)alloc((size_t)C_ * C_ * 2);
    unsigned short* sa_wkvt = (unsigned short*)alloc((size_t)C_ * 2 * KVH_ * D_ * 2); // [256][512]
    unsigned short* sa_wot = (unsigned short*)alloc((size_t)C_ * C_ * 2);
    unsigned short* ca_wqt = (unsigned short*)alloc((size_t)C_ * C_ * 2);
    unsigned short* ca_wkvt = (unsigned short*)alloc((size_t)C_ * 2 * KVH_ * D_ * 2);
    unsigned short* ca_wot = (unsigned short*)alloc((size_t)C_ * C_ * 2);
    float* bkv_sa = (float*)alloc(256 * 4);
    float* bkv_ca = (float*)alloc(256 * 4);
    unsigned short* w1t  = (unsigned short*)alloc((size_t)E_ * C_ * F_ * 2);
    unsigned short* w2t  = (unsigned short*)alloc((size_t)E_ * F_ * C_ * 2);
    float* gprobs  = (float*)alloc((size_t)BN_ * 8 * 4);
    int*   topi    = (int*)  alloc((size_t)BN_ * 2 * 4);
    float* gatesv  = (float*)alloc((size_t)BN_ * 2 * 4);
    int*   rowtok  = (int*)  alloc(17408 * 4);
    int*   slotidx = (int*)  alloc((size_t)BN_ * 2 * 4);
    int*   ctrl    = (int*)  alloc(256);
    float* psum    = (float*)((char*)ctrl + 128);
    (void)ws_size; (void)in_sizes; (void)n_in; (void)out_size;

    // ---- one-shot prep: all transposes + vis cast + bias packs + ctrl zero ----
    prep_all<<<18817, 256, 0, stream>>>(
        sa_wq, sa_wk, sa_wv, sa_wo, ca_wq, ca_wk, ca_wv, ca_wo,
        e_w1, e_w2, vis, sa_bk, sa_bv, ca_bk, ca_bv,
        sa_wqt, sa_wkvt, sa_wot, ca_wqt, ca_wkvt, ca_wot,
        w1t, w2t, visbf, bkv_sa, bkv_ca, ctrl);

    // ---- self-attention (residual written from x by Wo mode 4) ----
    ln_bf<<<BN_, 256, 0, stream>>>(x, ln1g, ln1b, hbz);
    dense_mfma<<<dim3(4, 64), 256, 0, stream>>>(hbz, sa_wqt, sa_bq, nullptr, nullptr, qbf, nullptr, C_, C_, 0, 0);
    dense_mfma<<<dim3(2, 64), 256, 0, stream>>>(hbz, sa_wkvt, bkv_sa, nullptr, nullptr, kbf, vtbf, 256, C_, 3, N_);
    attn_mfma<<<dim3(N_/64, B_*H_, 2), 256, 0, stream>>>(qbf, kbf, vtbf, nullptr, opart, lpart, N_, 1);
    attn_combine<<<(BN_*C_)/1024, 256, 0, stream>>>(opart, lpart, obf);
    dense_mfma<<<dim3(4, 64), 256, 0, stream>>>(obf, sa_wot, sa_bo, x, out, nullptr, nullptr, C_, C_, 4, 0);

    // ---- cross-attention ----
    ln_bf<<<BN_, 256, 0, stream>>>(out, ln2g, ln2b, hbz);
    dense_mfma<<<dim3(4, 64), 256, 0, stream>>>(hbz, ca_wqt, ca_bq, nullptr, nullptr, qbf, nullptr, C_, C_, 0, 0);
    dense_mfma<<<dim3(2, 18), 256, 0, stream>>>(visbf, ca_wkvt, bkv_ca, nullptr, nullptr, kbf, vtbf, 256, C_, 3, M_);
    attn_mfma<<<dim3(N_/64, B_*H_, 1), 256, 0, stream>>>(qbf, kbf, vtbf, obf, nullptr, nullptr, M_, 0);
    dense_mfma<<<dim3(4, 64), 256, 0, stream>>>(obf, ca_wot, ca_bo, nullptr, out, nullptr, nullptr, C_, C_, 1, 0);

    // ---- MoE ----
    ln_dual<<<BN_, 256, 0, stream>>>(out, ln3g, ln3b, hbuf, hbz);
    router_logits<<<BN_/4, 256, 0, stream>>>(hbuf, rw, rb, gprobs, topi, gatesv);
    router_reduce<<<16, 256, 0, stream>>>(gprobs, topi, ctrl, psum);
    router_offsets<<<1, 1, 0, stream>>>(ctrl);
    router_scatter<<<BN_/256, 256, 0, stream>>>(topi, gatesv, rowtok, slotidx, ctrl);
    moe_mfma<<<dim3(BN_/128, F_/128, E_), 256, 0, stream>>>(
        hbz, w1t, e_b1, moeH, rowtok, ctrl, F_, C_, 1);
    moe_mfma<<<dim3(BN_/128, C_/128, E_), 256, 0, stream>>>(
        moeH, w2t, e_b2, eoslots, rowtok, ctrl, C_, F_, 2);
    moe_combine<<<(BN_*C_)/1024, 256, 0, stream>>>(eoslots, slotidx, gatesv, out);
    aux_kernel<<<1, 1, 0, stream>>>(ctrl, psum, out + (size_t)BN_ * C_);
}

// Round 8
// 660.113 us; speedup vs baseline: 1.1055x; 1.1055x over previous
//
#include <hip/hip_runtime.h>
#include <cstddef>
#include <cstdint>

// Problem constants
#define B_   4
#define N_   2048
#define M_   576
#define C_   512
#define H_   8
#define KVH_ 2
#define D_   64
#define E_   8
#define F_   2048
#define BN_  (B_*N_)    // 8192 tokens
#define BM_  (B_*M_)    // 2304 vision tokens

typedef __attribute__((ext_vector_type(8))) short bf16x8;
typedef __attribute__((ext_vector_type(4))) float f32x4;

__device__ __forceinline__ unsigned short f2bf(float f) {
    union { float f; unsigned int u; } v; v.f = f;
    unsigned int r = v.u + 0x7FFFu + ((v.u >> 16) & 1u);
    return (unsigned short)(r >> 16);
}
__device__ __forceinline__ float bf2f(unsigned short u) {
    union { unsigned int u; float f; } v; v.u = ((unsigned int)u) << 16;
    return v.f;
}

// async global->LDS 16B/lane; LDS dest = wave-uniform base + lane*16
typedef __attribute__((address_space(1))) void glb_void;
typedef __attribute__((address_space(3))) void lds_void;
__device__ __forceinline__ void gl2lds16(const unsigned short* g, unsigned short* l) {
    __builtin_amdgcn_global_load_lds((glb_void*)g, (lds_void*)l, 16, 0, 0);
}

// ---------------------------------------------------------------------------
// prep_all: ALL weight transposes + vis cast + bias packs + ctrl zero in ONE
// launch. Block ranges are compile-time constants.
// ---------------------------------------------------------------------------
__global__ __launch_bounds__(256) void prep_all(
    const float* __restrict__ sa_wq, const float* __restrict__ sa_wk,
    const float* __restrict__ sa_wv, const float* __restrict__ sa_wo,
    const float* __restrict__ ca_wq, const float* __restrict__ ca_wk,
    const float* __restrict__ ca_wv, const float* __restrict__ ca_wo,
    const float* __restrict__ e_w1, const float* __restrict__ e_w2,
    const float* __restrict__ vis,
    const float* __restrict__ sa_bk, const float* __restrict__ sa_bv,
    const float* __restrict__ ca_bk, const float* __restrict__ ca_bv,
    unsigned short* __restrict__ sa_wqt, unsigned short* __restrict__ sa_wkvt,
    unsigned short* __restrict__ sa_wot,
    unsigned short* __restrict__ ca_wqt, unsigned short* __restrict__ ca_wkvt,
    unsigned short* __restrict__ ca_wot,
    unsigned short* __restrict__ w1t, unsigned short* __restrict__ w2t,
    unsigned short* __restrict__ visbf,
    float* __restrict__ bkv_sa, float* __restrict__ bkv_ca,
    int* __restrict__ ctrl)
{
    __shared__ float T[32][33];
    int t = blockIdx.x;
    int tid = threadIdx.x;

    if (t < 17664) {
        const float* W; unsigned short* Wt; int K, N, kt, nt;
        if (t < 1280) {
            if (t < 256)      { W = sa_wq; Wt = sa_wqt; K = 512; N = 512; int r = t;        nt = r & 15; kt = r >> 4; }
            else if (t < 320) { W = sa_wk; Wt = sa_wkvt;            K = 512; N = 128; int r = t - 256; nt = r & 3;  kt = r >> 2; }
            else if (t < 384) { W = sa_wv; Wt = sa_wkvt + 128*512;  K = 512; N = 128; int r = t - 320; nt = r & 3;  kt = r >> 2; }
            else if (t < 640) { W = sa_wo; Wt = sa_wot; K = 512; N = 512; int r = t - 384;  nt = r & 15; kt = r >> 4; }
            else if (t < 896) { W = ca_wq; Wt = ca_wqt; K = 512; N = 512; int r = t - 640;  nt = r & 15; kt = r >> 4; }
            else if (t < 960) { W = ca_wk; Wt = ca_wkvt;            K = 512; N = 128; int r = t - 896; nt = r & 3;  kt = r >> 2; }
            else if (t < 1024){ W = ca_wv; Wt = ca_wkvt + 128*512;  K = 512; N = 128; int r = t - 960; nt = r & 3;  kt = r >> 2; }
            else              { W = ca_wo; Wt = ca_wot; K = 512; N = 512; int r = t - 1024; nt = r & 15; kt = r >> 4; }
        } else if (t < 9472) {
            int r = t - 1280; int e = r >> 10; r &= 1023;
            W = e_w1 + (size_t)e * C_ * F_; Wt = w1t + (size_t)e * C_ * F_;
            K = C_; N = F_; nt = r & 63; kt = r >> 6;
        } else {
            int r = t - 9472; int e = r >> 10; r &= 1023;
            W = e_w2 + (size_t)e * F_ * C_; Wt = w2t + (size_t)e * F_ * C_;
            K = F_; N = C_; nt = r & 15; kt = r >> 4;
        }
        int rr = tid >> 3, c4 = (tid & 7) * 4;
        int k0 = kt * 32, n0 = nt * 32;
        float4 v = *(const float4*)&W[(size_t)(k0 + rr) * N + n0 + c4];
        T[rr][c4 + 0] = v.x; T[rr][c4 + 1] = v.y; T[rr][c4 + 2] = v.z; T[rr][c4 + 3] = v.w;
        __syncthreads();
        ushort4 o;
        o.x = f2bf(T[c4 + 0][rr]); o.y = f2bf(T[c4 + 1][rr]);
        o.z = f2bf(T[c4 + 2][rr]); o.w = f2bf(T[c4 + 3][rr]);
        *(ushort4*)&Wt[(size_t)(n0 + rr) * K + k0 + c4] = o;
    } else if (t < 18816) {
        int i = (t - 17664) * 1024 + tid * 4;
        float4 v = *(const float4*)(vis + i);
        ushort4 o;
        o.x = f2bf(v.x); o.y = f2bf(v.y); o.z = f2bf(v.z); o.w = f2bf(v.w);
        *(ushort4*)(visbf + i) = o;
    } else {
        if (tid < 128) {
            bkv_sa[tid]       = sa_bk[tid];
            bkv_sa[128 + tid] = sa_bv[tid];
            bkv_ca[tid]       = ca_bk[tid];
            bkv_ca[128 + tid] = ca_bv[tid];
        }
        if (tid < 32) ctrl[tid] = 0;
    }
}

// ---------------------------------------------------------------------------
// LayerNorm bf16 out (LN1/LN2)
// ---------------------------------------------------------------------------
__global__ __launch_bounds__(256) void ln_bf(const float* __restrict__ x,
    const float* __restrict__ g, const float* __restrict__ b, unsigned short* __restrict__ out)
{
    int row = blockIdx.x;
    const float* xr = x + (size_t)row * C_;
    float s = 0.f, ss = 0.f;
    for (int c = threadIdx.x; c < C_; c += 256) { float v = xr[c]; s += v; ss += v * v; }
    __shared__ float S1[256], S2[256];
    S1[threadIdx.x] = s; S2[threadIdx.x] = ss;
    __syncthreads();
    for (int o = 128; o > 0; o >>= 1) {
        if (threadIdx.x < o) { S1[threadIdx.x] += S1[threadIdx.x + o]; S2[threadIdx.x] += S2[threadIdx.x + o]; }
        __syncthreads();
    }
    float mu  = S1[0] * (1.f / C_);
    float var = S2[0] * (1.f / C_) - mu * mu;
    float inv = rsqrtf(var + 1e-6f);
    unsigned short* orow = out + (size_t)row * C_;
    for (int c = threadIdx.x; c < C_; c += 256)
        orow[c] = f2bf((xr[c] - mu) * inv * g[c] + b[c]);
}

// LayerNorm dual out: fp32 (router, bit-identical routing) + bf16 (GEMM input)
__global__ __launch_bounds__(256) void ln_dual(const float* __restrict__ x,
    const float* __restrict__ g, const float* __restrict__ b,
    float* __restrict__ outF, unsigned short* __restrict__ outBf)
{
    int row = blockIdx.x;
    const float* xr = x + (size_t)row * C_;
    float s = 0.f, ss = 0.f;
    for (int c = threadIdx.x; c < C_; c += 256) { float v = xr[c]; s += v; ss += v * v; }
    __shared__ float S1[256], S2[256];
    S1[threadIdx.x] = s; S2[threadIdx.x] = ss;
    __syncthreads();
    for (int o = 128; o > 0; o >>= 1) {
        if (threadIdx.x < o) { S1[threadIdx.x] += S1[threadIdx.x + o]; S2[threadIdx.x] += S2[threadIdx.x + o]; }
        __syncthreads();
    }
    float mu  = S1[0] * (1.f / C_);
    float var = S2[0] * (1.f / C_) - mu * mu;
    float inv = rsqrtf(var + 1e-6f);
    for (int c = threadIdx.x; c < C_; c += 256) {
        float v = (xr[c] - mu) * inv * g[c] + b[c];
        outF[(size_t)row * C_ + c] = v;
        outBf[(size_t)row * C_ + c] = f2bf(v);
    }
}

// ---------------------------------------------------------------------------
// Dense bf16 MFMA GEMM (async staging, XOR-swizzled unpadded LDS, BK=32).
// out = A[M][K] @ Bt[N][K]^T + bias. 128x128 tile, 4 waves 2x2 of 64x64.
// mode 0: bf16 out[M][N]; mode 1: fp32 out[M][N] +=; mode 4: out = xin + acc+bias
// mode 3: fused KV: cols<128 -> K natural [rows][128]; cols>=128 -> V
//         transposed per batch: outBf2[(b*128+(gc-128))*NkPer + m]
// ---------------------------------------------------------------------------
__global__ __launch_bounds__(256) void dense_mfma(
    const unsigned short* __restrict__ Abf,
    const unsigned short* __restrict__ Btbf,
    const float* __restrict__ bias,
    const float* __restrict__ xin,
    float* __restrict__ outF,
    unsigned short* __restrict__ outBf,
    unsigned short* __restrict__ outBf2,
    int N, int K, int mode, int NkPer)
{
    int row0 = blockIdx.y * 128;
    int col0 = blockIdx.x * 128;

    __shared__ unsigned short As[128 * 32];   // 64B rows, swizzled chunks
    __shared__ unsigned short Bs[128 * 32];

    int tid = threadIdx.x;
    int lane = tid & 63, wid = tid >> 6;
    int lrow = lane >> 2;
    int cswz = (((lane & 3) ^ ((lane >> 3) & 3)) << 3);   // shorts
    int ar0 = 16 * (wid * 2) + lrow;
    int ar1 = ar0 + 16;
    const unsigned short* gA0 = Abf + (size_t)(row0 + ar0) * K + cswz;
    const unsigned short* gA1 = Abf + (size_t)(row0 + ar1) * K + cswz;
    const unsigned short* gB0 = Btbf + (size_t)(col0 + ar0) * K + cswz;
    const unsigned short* gB1 = Btbf + (size_t)(col0 + ar1) * K + cswz;
    unsigned short* lA0 = As + (wid * 2) * 512;
    unsigned short* lA1 = lA0 + 512;
    unsigned short* lB0 = Bs + (wid * 2) * 512;
    unsigned short* lB1 = lB0 + 512;

    int wm0 = (wid & 1) * 64, wn0 = (wid >> 1) * 64;
    int lm = lane & 15, lq = lane >> 4;
    int swb = (lq ^ ((lm >> 1) & 3)) << 3;    // shorts
    int aoff[4], boff[4];
#pragma unroll
    for (int i = 0; i < 4; i++) {
        aoff[i] = (wm0 + 16 * i + lm) * 32 + swb;
        boff[i] = (wn0 + 16 * i + lm) * 32 + swb;
    }

    f32x4 acc[4][4];
#pragma unroll
    for (int i = 0; i < 4; i++)
#pragma unroll
        for (int j = 0; j < 4; j++)
            acc[i][j] = (f32x4){0.f, 0.f, 0.f, 0.f};

    for (int k0 = 0; k0 < K; k0 += 32) {
        __syncthreads();
        gl2lds16(gA0 + k0, lA0);
        gl2lds16(gA1 + k0, lA1);
        gl2lds16(gB0 + k0, lB0);
        gl2lds16(gB1 + k0, lB1);
        __syncthreads();

        bf16x8 av[4], bv[4];
#pragma unroll
        for (int i = 0; i < 4; i++) av[i] = *(const bf16x8*)&As[aoff[i]];
#pragma unroll
        for (int i = 0; i < 4; i++) bv[i] = *(const bf16x8*)&Bs[boff[i]];
#pragma unroll
        for (int mi = 0; mi < 4; mi++)
#pragma unroll
            for (int ni = 0; ni < 4; ni++)
                acc[mi][ni] = __builtin_amdgcn_mfma_f32_16x16x32_bf16(av[mi], bv[ni], acc[mi][ni], 0, 0, 0);
    }

#pragma unroll
    for (int mi = 0; mi < 4; mi++) {
#pragma unroll
        for (int ri = 0; ri < 4; ri++) {
            int gr = row0 + wm0 + 16 * mi + lq * 4 + ri;
            if (mode == 3) {
#pragma unroll
                for (int ni = 0; ni < 4; ni++) {
                    int gc = col0 + wn0 + 16 * ni + lm;
                    float v = acc[mi][ni][ri] + bias[gc];
                    if (gc < 128) {
                        outBf[(size_t)gr * 128 + gc] = f2bf(v);
                    } else {
                        int bb = gr / NkPer;
                        int mm = gr - bb * NkPer;
                        outBf2[((size_t)bb * 128 + (gc - 128)) * NkPer + mm] = f2bf(v);
                    }
                }
            } else if (mode == 1) {
                size_t orow = (size_t)gr * N;
#pragma unroll
                for (int ni = 0; ni < 4; ni++) {
                    int gc = col0 + wn0 + 16 * ni + lm;
                    outF[orow + gc] += acc[mi][ni][ri] + bias[gc];
                }
            } else if (mode == 4) {
                size_t orow = (size_t)gr * N;
#pragma unroll
                for (int ni = 0; ni < 4; ni++) {
                    int gc = col0 + wn0 + 16 * ni + lm;
                    outF[orow + gc] = xin[orow + gc] + acc[mi][ni][ri] + bias[gc];
                }
            } else {
                size_t orow = (size_t)gr * N;
#pragma unroll
                for (int ni = 0; ni < 4; ni++) {
                    int gc = col0 + wn0 + 16 * ni + lm;
                    outBf[orow + gc] = f2bf(acc[mi][ni][ri] + bias[gc]);
                }
            }
        }
    }
}

// ---------------------------------------------------------------------------
// MFMA flash attention (fixed-shift softmax, split-K capable) — validated r5/r6
// ---------------------------------------------------------------------------
__global__ __launch_bounds__(256) void attn_mfma(
    const unsigned short* __restrict__ Q,
    const unsigned short* __restrict__ K,
    const unsigned short* __restrict__ Vt,
    unsigned short* __restrict__ Obf,
    float* __restrict__ Opart,
    float* __restrict__ Lpart,
    int NkPer, int causal)
{
    __shared__ unsigned short Qs[64 * 72];
    __shared__ unsigned short Ks[64 * 72];
    __shared__ unsigned short Vs[64 * 72];
    unsigned short* Ps = Qs;

    int tid = threadIdx.x;
    int qt = blockIdx.x, bh = blockIdx.y, z = blockIdx.z;
    int b = bh >> 3, h = bh & 7, g = h >> 2;
    int q0 = qt * 64;

#pragma unroll
    for (int i = 0; i < 2; i++) {
        int s = tid + (i << 8);
        int r = s >> 3, c8 = (s & 7) << 3;
        *(uint4*)&Qs[r * 72 + c8] =
            *(const uint4*)&Q[(size_t)(b * N_ + q0 + r) * C_ + h * D_ + c8];
    }
    __syncthreads();

    int lane = tid & 63, wid = tid >> 6;
    int lm = lane & 15, lq = lane >> 4;
    int arow = wid * 16 + lm;

    bf16x8 qf[2];
    qf[0] = *(const bf16x8*)&Qs[arow * 72 + lq * 8];
    qf[1] = *(const bf16x8*)&Qs[arow * 72 + lq * 8 + 32];

    float lsum[4];
    f32x4 of[4];
#pragma unroll
    for (int i = 0; i < 4; i++) { lsum[i] = 0.f; of[i] = (f32x4){0.f,0.f,0.f,0.f}; }

    int nkt = causal ? (qt + 1) : ((NkPer + 63) >> 6);
    int nz = gridDim.z;
    int per = (nkt + nz - 1) / nz;
    int kt0 = z * per;
    int kt1 = min(nkt, kt0 + per);

    for (int kt = kt0; kt < kt1; kt++) {
        int k0 = kt << 6;
        __syncthreads();
#pragma unroll
        for (int i = 0; i < 2; i++) {
            int s = tid + (i << 8);
            int r = s >> 3, c8 = (s & 7) << 3;
            *(uint4*)&Ks[r * 72 + c8] =
                *(const uint4*)&K[(size_t)(b * NkPer + k0 + r) * (KVH_ * D_) + g * D_ + c8];
            *(uint4*)&Vs[r * 72 + c8] =
                *(const uint4*)&Vt[(size_t)(b * (KVH_ * D_) + g * D_ + r) * NkPer + k0 + c8];
        }
        __syncthreads();

        f32x4 sf[4];
#pragma unroll
        for (int i = 0; i < 4; i++) sf[i] = (f32x4){0.f,0.f,0.f,0.f};
#pragma unroll
        for (int ks = 0; ks < 2; ks++) {
#pragma unroll
            for (int ni = 0; ni < 4; ni++) {
                bf16x8 bv = *(const bf16x8*)&Ks[(16 * ni + lm) * 72 + lq * 8 + 32 * ks];
                sf[ni] = __builtin_amdgcn_mfma_f32_16x16x32_bf16(qf[ks], bv, sf[ni], 0, 0, 0);
            }
        }

        bool diag = causal && (k0 + 63 > q0 + wid * 16);
#pragma unroll
        for (int ni = 0; ni < 4; ni++)
#pragma unroll
            for (int ri = 0; ri < 4; ri++) {
                float v = sf[ni][ri] * 0.125f - 8.f;
                if (diag && (k0 + 16 * ni + lm > q0 + wid * 16 + lq * 4 + ri)) v = -1e30f;
                float p = __expf(v);
                sf[ni][ri] = p;
                lsum[ri] += p;
            }

#pragma unroll
        for (int ni = 0; ni < 4; ni++)
#pragma unroll
            for (int ri = 0; ri < 4; ri++)
                Ps[(wid * 16 + lq * 4 + ri) * 72 + 16 * ni + lm] = f2bf(sf[ni][ri]);
        __syncthreads();

        bf16x8 pf0 = *(const bf16x8*)&Ps[arow * 72 + lq * 8];
        bf16x8 pf1 = *(const bf16x8*)&Ps[arow * 72 + lq * 8 + 32];
#pragma unroll
        for (int ni = 0; ni < 4; ni++) {
            bf16x8 vv0 = *(const bf16x8*)&Vs[(16 * ni + lm) * 72 + lq * 8];
            bf16x8 vv1 = *(const bf16x8*)&Vs[(16 * ni + lm) * 72 + lq * 8 + 32];
            of[ni] = __builtin_amdgcn_mfma_f32_16x16x32_bf16(pf0, vv0, of[ni], 0, 0, 0);
            of[ni] = __builtin_amdgcn_mfma_f32_16x16x32_bf16(pf1, vv1, of[ni], 0, 0, 0);
        }
    }

#pragma unroll
    for (int ri = 0; ri < 4; ri++) {
        float s = lsum[ri];
        s += __shfl_xor(s, 1);
        s += __shfl_xor(s, 2);
        s += __shfl_xor(s, 4);
        s += __shfl_xor(s, 8);
        lsum[ri] = s;
    }

    if (nz == 1) {
#pragma unroll
        for (int ri = 0; ri < 4; ri++) {
            float inv = 1.f / lsum[ri];
            int q = q0 + wid * 16 + lq * 4 + ri;
            size_t orow = (size_t)(b * N_ + q) * C_ + h * D_;
#pragma unroll
            for (int ni = 0; ni < 4; ni++)
                Obf[orow + 16 * ni + lm] = f2bf(of[ni][ri] * inv);
        }
    } else {
        size_t zofs = (size_t)z * BN_ * C_;
#pragma unroll
        for (int ri = 0; ri < 4; ri++) {
            int q = q0 + wid * 16 + lq * 4 + ri;
            size_t orow = zofs + (size_t)(b * N_ + q) * C_ + h * D_;
#pragma unroll
            for (int ni = 0; ni < 4; ni++)
                Opart[orow + 16 * ni + lm] = of[ni][ri];
            if (lm == 0)
                Lpart[(size_t)z * (B_ * H_ * N_) + bh * N_ + q] = lsum[ri];
        }
    }
}

__global__ __launch_bounds__(256) void attn_combine(const float* __restrict__ Opart,
    const float* __restrict__ Lpart, unsigned short* __restrict__ Obf)
{
    int flat = (blockIdx.x * 256 + threadIdx.x) * 4;
    int row = flat >> 9, col = flat & 511;
    int b = row >> 11, q = row & (N_ - 1), h = col >> 6;
    int bh = b * 8 + h;
    float l = Lpart[bh * N_ + q] + Lpart[B_ * H_ * N_ + bh * N_ + q];
    float inv = 1.f / l;
    float4 o0 = *(const float4*)&Opart[flat];
    float4 o1 = *(const float4*)&Opart[(size_t)BN_ * C_ + flat];
    ushort4 o;
    o.x = f2bf((o0.x + o1.x) * inv); o.y = f2bf((o0.y + o1.y) * inv);
    o.z = f2bf((o0.z + o1.z) * inv); o.w = f2bf((o0.w + o1.w) * inv);
    *(ushort4*)&Obf[flat] = o;
}

// ---------------------------------------------------------------------------
// Router (atomic-free logits + reduce + aggregated scatter w/ slot record)
// ---------------------------------------------------------------------------
__global__ __launch_bounds__(256) void router_logits(const float* __restrict__ X,
    const float* __restrict__ RW, const float* __restrict__ RB,
    float* __restrict__ gprobs, int* __restrict__ topi, float* __restrict__ gatesv)
{
    int lane = threadIdx.x & 63;
    int t = blockIdx.x * 4 + (threadIdx.x >> 6);
    const float* xr = X + (size_t)t * C_;
    float p[8] = {};
    for (int i = 0; i < 8; i++) {
        int c = i * 64 + lane;
        float xv = xr[c];
#pragma unroll
        for (int e = 0; e < 8; e++) p[e] = fmaf(xv, RW[c * 8 + e], p[e]);
    }
#pragma unroll
    for (int e = 0; e < 8; e++) {
        float v = p[e];
        v += __shfl_xor(v, 32, 64);
        v += __shfl_xor(v, 16, 64);
        v += __shfl_xor(v, 8, 64);
        v += __shfl_xor(v, 4, 64);
        v += __shfl_xor(v, 2, 64);
        v += __shfl_xor(v, 1, 64);
        p[e] = v;
    }
    if (lane == 0) {
        float logits[8], mx = -1e30f;
        for (int e = 0; e < 8; e++) { logits[e] = p[e] + RB[e]; mx = fmaxf(mx, logits[e]); }
        float pr[8], sum = 0.f;
        for (int e = 0; e < 8; e++) { pr[e] = expf(logits[e] - mx); sum += pr[e]; }
        float inv = 1.f / sum;
        for (int e = 0; e < 8; e++) { pr[e] *= inv; gprobs[t * 8 + e] = pr[e]; }
        int i1 = 0;
        for (int e = 1; e < 8; e++) if (pr[e] > pr[i1]) i1 = e;
        int i2 = (i1 == 0) ? 1 : 0;
        for (int e = 0; e < 8; e++) if (e != i1 && pr[e] > pr[i2]) i2 = e;
        float v1 = pr[i1], v2 = pr[i2], sg = 1.f / (v1 + v2);
        topi[t * 2]     = i1;  topi[t * 2 + 1]   = i2;
        gatesv[t * 2]   = v1 * sg;  gatesv[t * 2 + 1] = v2 * sg;
    }
}

__global__ __launch_bounds__(256) void router_reduce(const float* __restrict__ gprobs,
    const int* __restrict__ topi, int* __restrict__ ctrl, float* __restrict__ psum)
{
    __shared__ float fs[256];
    __shared__ int   is_[256];
    int bid = blockIdx.x, tid = threadIdx.x;
    if (bid < 8) {
        float s = 0.f;
        for (int t = tid; t < BN_; t += 256) s += gprobs[t * 8 + bid];
        fs[tid] = s; __syncthreads();
        for (int o = 128; o > 0; o >>= 1) { if (tid < o) fs[tid] += fs[tid + o]; __syncthreads(); }
        if (tid == 0) psum[bid] = fs[0];
    } else {
        int e = bid - 8, c = 0;
        for (int i = tid; i < BN_ * 2; i += 256) c += (topi[i] == e);
        is_[tid] = c; __syncthreads();
        for (int o = 128; o > 0; o >>= 1) { if (tid < o) is_[tid] += is_[tid + o]; __syncthreads(); }
        if (tid == 0) ctrl[e] = is_[0];
    }
}

__global__ void router_offsets(int* __restrict__ ctrl)
{
    if (threadIdx.x == 0 && blockIdx.x == 0) {
        int off = 0;
        for (int e = 0; e < 8; e++) {
            ctrl[16 + e] = off;
            off += (ctrl[e] + 127) & ~127;
        }
        ctrl[24] = off;
    }
}

__global__ __launch_bounds__(256) void router_scatter(const int* __restrict__ topi,
    const float* __restrict__ gatesv, int* __restrict__ rowtok,
    int* __restrict__ slotidx, int* __restrict__ ctrl)
{
    __shared__ int lcnt[8];
    __shared__ int lbase[8];
    int tid = threadIdx.x;
    int t = blockIdx.x * 256 + tid;
    if (tid < 8) lcnt[tid] = 0;
    __syncthreads();
    int e0 = topi[t * 2], e1 = topi[t * 2 + 1];
    int p0 = atomicAdd(&lcnt[e0], 1);
    int p1 = atomicAdd(&lcnt[e1], 1);
    __syncthreads();
    if (tid < 8) lbase[tid] = atomicAdd(&ctrl[8 + tid], lcnt[tid]);
    __syncthreads();
    int s0 = ctrl[16 + e0] + lbase[e0] + p0;
    int s1 = ctrl[16 + e1] + lbase[e1] + p1;
    rowtok[s0] = t;
    rowtok[s1] = t;
    slotidx[t * 2]     = s0;
    slotidx[t * 2 + 1] = s1;
}

// ---------------------------------------------------------------------------
// MoE bf16 MFMA GEMM, BK=64 (half the barriers of BK=32), async staging.
// Grid: x = col-block, y = row-block, z = expert (r6 order).
// LDS rows are 64 shorts (128 B); phys chunk = logical ^ (row & 7):
// staging lane (row=lane>>3, phys=lane&7) fetches source chunk (lane&7)^(row&7);
// frag reads spread 8 distinct chunks across the 16-lane group (2-way = free).
// mode 1: A = Xbf gathered by rowtok; out = gelu(acc+b1) -> bf16 [slot][F]
// mode 2: A = Hbuf rows off+...;      out = acc+b2       -> bf16 [slot][C]
// ---------------------------------------------------------------------------
__global__ __launch_bounds__(256) void moe_mfma(
    const unsigned short* __restrict__ Abf,
    const unsigned short* __restrict__ Btbf,
    const float* __restrict__ biasAll,
    unsigned short* __restrict__ outBf,
    const int* __restrict__ rowtok,
    const int* __restrict__ ctrl,
    int N, int K, int mode)
{
    int e = blockIdx.z;
    int cnt = ctrl[e];
    int row0 = blockIdx.y * 128;
    if (row0 >= cnt) return;
    int off = ctrl[16 + e];
    int col0 = blockIdx.x * 128;
    const unsigned short* Bt = Btbf + (size_t)e * N * K;
    const float* bias = biasAll + (size_t)e * N;

    __shared__ unsigned short As[128 * 64];   // 16 KB
    __shared__ unsigned short Bs[128 * 64];   // 16 KB
    __shared__ int toks[128];

    int tid = threadIdx.x;
    if (mode == 1 && tid < 128) {
        int gl = row0 + tid;
        toks[tid] = rowtok[off + (gl < cnt ? gl : 0)];
    }
    __syncthreads();

    int lane = tid & 63, wid = tid >> 6;
    // staging: wave wid covers rows [wid*32, wid*32+32), 4 issues x 8 rows
    int r8 = lane >> 3;
    size_t asrc[4], bsrc[4];
    unsigned short *adst[4], *bdst[4];
#pragma unroll
    for (int i = 0; i < 4; i++) {
        int rA = wid * 32 + i * 8 + r8;
        int srcc = (((lane & 7) ^ (rA & 7)) << 3);      // shorts
        size_t arow = (mode == 1) ? (size_t)toks[rA] * K
                                  : (size_t)(off + row0 + rA) * K;
        asrc[i] = arow + srcc;
        bsrc[i] = (size_t)(col0 + rA) * K + srcc;
        adst[i] = As + (wid * 32 + i * 8) * 64;
        bdst[i] = Bs + (wid * 32 + i * 8) * 64;
    }

    int wm0 = (wid & 1) * 64, wn0 = (wid >> 1) * 64;
    int lm = lane & 15, lq = lane >> 4;
    int x7 = lm & 7;
    // frag offsets: [row i][k32 half]
    int aoff[4][2], boff[4][2];
#pragma unroll
    for (int i = 0; i < 4; i++) {
#pragma unroll
        for (int ks = 0; ks < 2; ks++) {
            int swz = (((ks << 2) + lq) ^ x7) << 3;
            aoff[i][ks] = (wm0 + 16 * i + lm) * 64 + swz;
            boff[i][ks] = (wn0 + 16 * i + lm) * 64 + swz;
        }
    }

    f32x4 acc[4][4];
#pragma unroll
    for (int i = 0; i < 4; i++)
#pragma unroll
        for (int j = 0; j < 4; j++)
            acc[i][j] = (f32x4){0.f, 0.f, 0.f, 0.f};

    for (int k0 = 0; k0 < K; k0 += 64) {
        __syncthreads();
#pragma unroll
        for (int i = 0; i < 4; i++) {
            gl2lds16(Abf + asrc[i] + k0, adst[i]);
            gl2lds16(Bt  + bsrc[i] + k0, bdst[i]);
        }
        __syncthreads();

#pragma unroll
        for (int ks = 0; ks < 2; ks++) {
            bf16x8 av[4], bv[4];
#pragma unroll
            for (int i = 0; i < 4; i++) av[i] = *(const bf16x8*)&As[aoff[i][ks]];
#pragma unroll
            for (int i = 0; i < 4; i++) bv[i] = *(const bf16x8*)&Bs[boff[i][ks]];
#pragma unroll
            for (int mi = 0; mi < 4; mi++)
#pragma unroll
                for (int ni = 0; ni < 4; ni++)
                    acc[mi][ni] = __builtin_amdgcn_mfma_f32_16x16x32_bf16(av[mi], bv[ni], acc[mi][ni], 0, 0, 0);
        }
    }

    // epilogue: direct scattered b16 stores (r6-validated; conflicts N/A)
#pragma unroll
    for (int mi = 0; mi < 4; mi++) {
#pragma unroll
        for (int ri = 0; ri < 4; ri++) {
            int gl = row0 + wm0 + 16 * mi + lq * 4 + ri;
            size_t orow = (size_t)(off + gl) * N;
            if (mode == 1) {
#pragma unroll
                for (int ni = 0; ni < 4; ni++) {
                    int gc = col0 + wn0 + 16 * ni + lm;
                    float hv = 0.f;
                    if (gl < cnt) {
                        float xv = acc[mi][ni][ri] + bias[gc];
                        float z = 0.7978845608f * xv * fmaf(0.044715f, xv * xv, 1.f);
                        hv = __fdividef(xv, 1.f + __expf(-2.f * z));
                    }
                    outBf[orow + gc] = f2bf(hv);
                }
            } else {
#pragma unroll
                for (int ni = 0; ni < 4; ni++) {
                    int gc = col0 + wn0 + 16 * ni + lm;
                    outBf[orow + gc] = f2bf(acc[mi][ni][ri] + bias[gc]);
                }
            }
        }
    }
}

// combine: out[t][c] += g0*eo[s0][c] + g1*eo[s1][c]
__global__ __launch_bounds__(256) void moe_combine(const unsigned short* __restrict__ slots,
    const int* __restrict__ slotidx, const float* __restrict__ gatesv,
    float* __restrict__ out)
{
    int flat = (blockIdx.x * 256 + threadIdx.x) * 4;
    int t = flat >> 9, c = flat & 511;
    int s0 = slotidx[t * 2], s1 = slotidx[t * 2 + 1];
    float g0 = gatesv[t * 2], g1 = gatesv[t * 2 + 1];
    ushort4 a = *(const ushort4*)&slots[(size_t)s0 * C_ + c];
    ushort4 b = *(const ushort4*)&slots[(size_t)s1 * C_ + c];
    float4 o = *(float4*)&out[flat];
    o.x += g0 * bf2f(a.x) + g1 * bf2f(b.x);
    o.y += g0 * bf2f(a.y) + g1 * bf2f(b.y);
    o.z += g0 * bf2f(a.z) + g1 * bf2f(b.z);
    o.w += g0 * bf2f(a.w) + g1 * bf2f(b.w);
    *(float4*)&out[flat] = o;
}

// aux = E * sum_e (counts[e]/BN) * (psum[e]/BN)
__global__ void aux_kernel(const int* __restrict__ ctrl, const float* __restrict__ psum,
                           float* __restrict__ outaux)
{
    if (threadIdx.x == 0 && blockIdx.x == 0) {
        float s = 0.f;
        for (int e = 0; e < 8; e++)
            s += ((float)ctrl[e] / (float)BN_) * (psum[e] / (float)BN_);
        outaux[0] = 8.f * s;
    }
}

// ---------------------------------------------------------------------------
extern "C" void kernel_launch(void* const* d_in, const int* in_sizes, int n_in,
                              void* d_out, int out_size, void* d_ws, size_t ws_size,
                              hipStream_t stream)
{
    const float* x      = (const float*)d_in[0];
    const float* vis    = (const float*)d_in[1];
    const float* ln1g   = (const float*)d_in[2];
    const float* ln1b   = (const float*)d_in[3];
    const float* ln2g   = (const float*)d_in[4];
    const float* ln2b   = (const float*)d_in[5];
    const float* ln3g   = (const float*)d_in[6];
    const float* ln3b   = (const float*)d_in[7];
    const float* sa_wq  = (const float*)d_in[8];
    const float* sa_bq  = (const float*)d_in[9];
    const float* sa_wk  = (const float*)d_in[10];
    const float* sa_bk  = (const float*)d_in[11];
    const float* sa_wv  = (const float*)d_in[12];
    const float* sa_bv  = (const float*)d_in[13];
    const float* sa_wo  = (const float*)d_in[14];
    const float* sa_bo  = (const float*)d_in[15];
    const float* ca_wq  = (const float*)d_in[16];
    const float* ca_bq  = (const float*)d_in[17];
    const float* ca_wk  = (const float*)d_in[18];
    const float* ca_bk  = (const float*)d_in[19];
    const float* ca_wv  = (const float*)d_in[20];
    const float* ca_bv  = (const float*)d_in[21];
    const float* ca_wo  = (const float*)d_in[22];
    const float* ca_bo  = (const float*)d_in[23];
    const float* rw     = (const float*)d_in[24];
    const float* rb     = (const float*)d_in[25];
    const float* e_w1   = (const float*)d_in[26];
    const float* e_b1   = (const float*)d_in[27];
    const float* e_w2   = (const float*)d_in[28];
    const float* e_b2   = (const float*)d_in[29];

    float* out = (float*)d_out;

    char* ws = (char*)d_ws;
    size_t off = 0;
    auto alloc = [&](size_t bytes) -> void* {
        void* p = ws + off;
        off = (off + bytes + 255) & ~(size_t)255;
        return p;
    };
    float* hbuf    = (float*)alloc((size_t)BN_ * C_ * 4);                   // LN3 fp32
    unsigned short* hbz = (unsigned short*)alloc((size_t)BN_ * C_ * 2);     // bf16 LN out
    unsigned short* visbf = (unsigned short*)alloc((size_t)BM_ * C_ * 2);
    // eoslots (bf16 [17408][C] = 17.9 MB) overlays hbuf+hbz (25.2 MB), both
    // dead during MoE GEMM2/combine.
    unsigned short* eoslots = (unsigned short*)hbuf;
    // union region: attention temps overlap MoE H buffer (71.3 MB)
    char* ureg = (char*)alloc((size_t)17408 * F_ * 2);
    unsigned short* moeH = (unsigned short*)ureg;
    unsigned short* qbf  = (unsigned short*)(ureg);                          // 8.4 MB
    unsigned short* obf  = (unsigned short*)(ureg + (size_t)BN_ * C_ * 2);   // 8.4 MB
    unsigned short* kbf  = (unsigned short*)(ureg + (size_t)BN_ * C_ * 4);   // 2.1 MB
    unsigned short* vtbf = (unsigned short*)(ureg + (size_t)BN_ * C_ * 4 + (size_t)BN_ * KVH_ * D_ * 2);
    float* opart = (float*)(ureg + (size_t)BN_ * C_ * 4 + (size_t)BN_ * KVH_ * D_ * 4); // 2 x 16.8 MB
    float* lpart = (float*)(ureg + (size_t)BN_ * C_ * 4 + (size_t)BN_ * KVH_ * D_ * 4
                                 + (size_t)2 * BN_ * C_ * 4);
    unsigned short* sa_wqt = (unsigned short*)alloc((size_t)C_ * C_ * 2);
    unsigned short* sa_wkvt = (unsigned short*)alloc((size_t)C_ * 2 * KVH_ * D_ * 2); // [256][512]
    unsigned short* sa_wot = (unsigned short*)alloc((size_t)C_ * C_ * 2);
    unsigned short* ca_wqt = (unsigned short*)alloc((size_t)C_ * C_ * 2);
    unsigned short* ca_wkvt = (unsigned short*)alloc((size_t)C_ * 2 * KVH_ * D_ * 2);
    unsigned short* ca_wot = (unsigned short*)alloc((size_t)C_ * C_ * 2);
    float* bkv_sa = (float*)alloc(256 * 4);
    float* bkv_ca = (float*)alloc(256 * 4);
    unsigned short* w1t  = (unsigned short*)alloc((size_t)E_ * C_ * F_ * 2);
    unsigned short* w2t  = (unsigned short*)alloc((size_t)E_ * F_ * C_ * 2);
    float* gprobs  = (float*)alloc((size_t)BN_ * 8 * 4);
    int*   topi    = (int*)  alloc((size_t)BN_ * 2 * 4);
    float* gatesv  = (float*)alloc((size_t)BN_ * 2 * 4);
    int*   rowtok  = (int*)  alloc(17408 * 4);
    int*   slotidx = (int*)  alloc((size_t)BN_ * 2 * 4);
    int*   ctrl    = (int*)  alloc(256);
    float* psum    = (float*)((char*)ctrl + 128);
    (void)ws_size; (void)in_sizes; (void)n_in; (void)out_size;

    // ---- one-shot prep: all transposes + vis cast + bias packs + ctrl zero ----
    prep_all<<<18817, 256, 0, stream>>>(
        sa_wq, sa_wk, sa_wv, sa_wo, ca_wq, ca_wk, ca_wv, ca_wo,
        e_w1, e_w2, vis, sa_bk, sa_bv, ca_bk, ca_bv,
        sa_wqt, sa_wkvt, sa_wot, ca_wqt, ca_wkvt, ca_wot,
        w1t, w2t, visbf, bkv_sa, bkv_ca, ctrl);

    // ---- self-attention (residual written from x by Wo mode 4) ----
    ln_bf<<<BN_, 256, 0, stream>>>(x, ln1g, ln1b, hbz);
    dense_mfma<<<dim3(4, 64), 256, 0, stream>>>(hbz, sa_wqt, sa_bq, nullptr, nullptr, qbf, nullptr, C_, C_, 0, 0);
    dense_mfma<<<dim3(2, 64), 256, 0, stream>>>(hbz, sa_wkvt, bkv_sa, nullptr, nullptr, kbf, vtbf, 256, C_, 3, N_);
    attn_mfma<<<dim3(N_/64, B_*H_, 2), 256, 0, stream>>>(qbf, kbf, vtbf, nullptr, opart, lpart, N_, 1);
    attn_combine<<<(BN_*C_)/1024, 256, 0, stream>>>(opart, lpart, obf);
    dense_mfma<<<dim3(4, 64), 256, 0, stream>>>(obf, sa_wot, sa_bo, x, out, nullptr, nullptr, C_, C_, 4, 0);

    // ---- cross-attention ----
    ln_bf<<<BN_, 256, 0, stream>>>(out, ln2g, ln2b, hbz);
    dense_mfma<<<dim3(4, 64), 256, 0, stream>>>(hbz, ca_wqt, ca_bq, nullptr, nullptr, qbf, nullptr, C_, C_, 0, 0);
    dense_mfma<<<dim3(2, 18), 256, 0, stream>>>(visbf, ca_wkvt, bkv_ca, nullptr, nullptr, kbf, vtbf, 256, C_, 3, M_);
    attn_mfma<<<dim3(N_/64, B_*H_, 1), 256, 0, stream>>>(qbf, kbf, vtbf, obf, nullptr, nullptr, M_, 0);
    dense_mfma<<<dim3(4, 64), 256, 0, stream>>>(obf, ca_wot, ca_bo, nullptr, out, nullptr, nullptr, C_, C_, 1, 0);

    // ---- MoE ----
    ln_dual<<<BN_, 256, 0, stream>>>(out, ln3g, ln3b, hbuf, hbz);
    router_logits<<<BN_/4, 256, 0, stream>>>(hbuf, rw, rb, gprobs, topi, gatesv);
    router_reduce<<<16, 256, 0, stream>>>(gprobs, topi, ctrl, psum);
    router_offsets<<<1, 1, 0, stream>>>(ctrl);
    router_scatter<<<BN_/256, 256, 0, stream>>>(topi, gatesv, rowtok, slotidx, ctrl);
    moe_mfma<<<dim3(F_/128, BN_/128, E_), 256, 0, stream>>>(
        hbz, w1t, e_b1, moeH, rowtok, ctrl, F_, C_, 1);
    moe_mfma<<<dim3(C_/128, BN_/128, E_), 256, 0, stream>>>(
        moeH, w2t, e_b2, eoslots, rowtok, ctrl, C_, F_, 2);
    moe_combine<<<(BN_*C_)/1024, 256, 0, stream>>>(eoslots, slotidx, gatesv, out);
    aux_kernel<<<1, 1, 0, stream>>>(ctrl, psum, out + (size_t)BN_ * C_);
}

// Round 9
// 649.981 us; speedup vs baseline: 1.1227x; 1.0156x over previous
//
#include <hip/hip_runtime.h>
#include <cstddef>
#include <cstdint>

// Problem constants
#define B_   4
#define N_   2048
#define M_   576
#define C_   512
#define H_   8
#define KVH_ 2
#define D_   64
#define E_   8
#define F_   2048
#define BN_  (B_*N_)    // 8192 tokens
#define BM_  (B_*M_)    // 2304 vision tokens

typedef __attribute__((ext_vector_type(8))) short bf16x8;
typedef __attribute__((ext_vector_type(4))) float f32x4;

__device__ __forceinline__ unsigned short f2bf(float f) {
    union { float f; unsigned int u; } v; v.f = f;
    unsigned int r = v.u + 0x7FFFu + ((v.u >> 16) & 1u);
    return (unsigned short)(r >> 16);
}
__device__ __forceinline__ float bf2f(unsigned short u) {
    union { unsigned int u; float f; } v; v.u = ((unsigned int)u) << 16;
    return v.f;
}

// async global->LDS 16B/lane; LDS dest = wave-uniform base + lane*16
typedef __attribute__((address_space(1))) void glb_void;
typedef __attribute__((address_space(3))) void lds_void;
__device__ __forceinline__ void gl2lds16(const unsigned short* g, unsigned short* l) {
    __builtin_amdgcn_global_load_lds((glb_void*)g, (lds_void*)l, 16, 0, 0);
}

// ---------------------------------------------------------------------------
// prep_all: ALL weight transposes + vis cast + bias packs + ctrl zero in ONE
// launch. sa_wqt/sa_wkvt are adjacent allocations -> packed [768][512] QKV.
// ---------------------------------------------------------------------------
__global__ __launch_bounds__(256) void prep_all(
    const float* __restrict__ sa_wq, const float* __restrict__ sa_wk,
    const float* __restrict__ sa_wv, const float* __restrict__ sa_wo,
    const float* __restrict__ ca_wq, const float* __restrict__ ca_wk,
    const float* __restrict__ ca_wv, const float* __restrict__ ca_wo,
    const float* __restrict__ e_w1, const float* __restrict__ e_w2,
    const float* __restrict__ vis,
    const float* __restrict__ sa_bq,
    const float* __restrict__ sa_bk, const float* __restrict__ sa_bv,
    const float* __restrict__ ca_bk, const float* __restrict__ ca_bv,
    unsigned short* __restrict__ sa_wqt, unsigned short* __restrict__ sa_wkvt,
    unsigned short* __restrict__ sa_wot,
    unsigned short* __restrict__ ca_wqt, unsigned short* __restrict__ ca_wkvt,
    unsigned short* __restrict__ ca_wot,
    unsigned short* __restrict__ w1t, unsigned short* __restrict__ w2t,
    unsigned short* __restrict__ visbf,
    float* __restrict__ bqkv_sa, float* __restrict__ bkv_ca,
    int* __restrict__ ctrl)
{
    __shared__ float T[32][33];
    int t = blockIdx.x;
    int tid = threadIdx.x;

    if (t < 17664) {
        const float* W; unsigned short* Wt; int K, N, kt, nt;
        if (t < 1280) {
            if (t < 256)      { W = sa_wq; Wt = sa_wqt; K = 512; N = 512; int r = t;        nt = r & 15; kt = r >> 4; }
            else if (t < 320) { W = sa_wk; Wt = sa_wkvt;            K = 512; N = 128; int r = t - 256; nt = r & 3;  kt = r >> 2; }
            else if (t < 384) { W = sa_wv; Wt = sa_wkvt + 128*512;  K = 512; N = 128; int r = t - 320; nt = r & 3;  kt = r >> 2; }
            else if (t < 640) { W = sa_wo; Wt = sa_wot; K = 512; N = 512; int r = t - 384;  nt = r & 15; kt = r >> 4; }
            else if (t < 896) { W = ca_wq; Wt = ca_wqt; K = 512; N = 512; int r = t - 640;  nt = r & 15; kt = r >> 4; }
            else if (t < 960) { W = ca_wk; Wt = ca_wkvt;            K = 512; N = 128; int r = t - 896; nt = r & 3;  kt = r >> 2; }
            else if (t < 1024){ W = ca_wv; Wt = ca_wkvt + 128*512;  K = 512; N = 128; int r = t - 960; nt = r & 3;  kt = r >> 2; }
            else              { W = ca_wo; Wt = ca_wot; K = 512; N = 512; int r = t - 1024; nt = r & 15; kt = r >> 4; }
        } else if (t < 9472) {
            int r = t - 1280; int e = r >> 10; r &= 1023;
            W = e_w1 + (size_t)e * C_ * F_; Wt = w1t + (size_t)e * C_ * F_;
            K = C_; N = F_; nt = r & 63; kt = r >> 6;
        } else {
            int r = t - 9472; int e = r >> 10; r &= 1023;
            W = e_w2 + (size_t)e * F_ * C_; Wt = w2t + (size_t)e * F_ * C_;
            K = F_; N = C_; nt = r & 15; kt = r >> 4;
        }
        int rr = tid >> 3, c4 = (tid & 7) * 4;
        int k0 = kt * 32, n0 = nt * 32;
        float4 v = *(const float4*)&W[(size_t)(k0 + rr) * N + n0 + c4];
        T[rr][c4 + 0] = v.x; T[rr][c4 + 1] = v.y; T[rr][c4 + 2] = v.z; T[rr][c4 + 3] = v.w;
        __syncthreads();
        ushort4 o;
        o.x = f2bf(T[c4 + 0][rr]); o.y = f2bf(T[c4 + 1][rr]);
        o.z = f2bf(T[c4 + 2][rr]); o.w = f2bf(T[c4 + 3][rr]);
        *(ushort4*)&Wt[(size_t)(n0 + rr) * K + k0 + c4] = o;
    } else if (t < 18816) {
        int i = (t - 17664) * 1024 + tid * 4;
        float4 v = *(const float4*)(vis + i);
        ushort4 o;
        o.x = f2bf(v.x); o.y = f2bf(v.y); o.z = f2bf(v.z); o.w = f2bf(v.w);
        *(ushort4*)(visbf + i) = o;
    } else {
        // packed bias for fused self-QKV: [bq(512) | bk(128) | bv(128)]
        for (int c = tid; c < 512; c += 256) bqkv_sa[c] = sa_bq[c];
        if (tid < 128) {
            bqkv_sa[512 + tid] = sa_bk[tid];
            bqkv_sa[640 + tid] = sa_bv[tid];
            bkv_ca[tid]        = ca_bk[tid];
            bkv_ca[128 + tid]  = ca_bv[tid];
        }
        if (tid < 32) ctrl[tid] = 0;
    }
}

// ---------------------------------------------------------------------------
// LayerNorm bf16 out (LN1/LN2)
// ---------------------------------------------------------------------------
__global__ __launch_bounds__(256) void ln_bf(const float* __restrict__ x,
    const float* __restrict__ g, const float* __restrict__ b, unsigned short* __restrict__ out)
{
    int row = blockIdx.x;
    const float* xr = x + (size_t)row * C_;
    float s = 0.f, ss = 0.f;
    for (int c = threadIdx.x; c < C_; c += 256) { float v = xr[c]; s += v; ss += v * v; }
    __shared__ float S1[256], S2[256];
    S1[threadIdx.x] = s; S2[threadIdx.x] = ss;
    __syncthreads();
    for (int o = 128; o > 0; o >>= 1) {
        if (threadIdx.x < o) { S1[threadIdx.x] += S1[threadIdx.x + o]; S2[threadIdx.x] += S2[threadIdx.x + o]; }
        __syncthreads();
    }
    float mu  = S1[0] * (1.f / C_);
    float var = S2[0] * (1.f / C_) - mu * mu;
    float inv = rsqrtf(var + 1e-6f);
    unsigned short* orow = out + (size_t)row * C_;
    for (int c = threadIdx.x; c < C_; c += 256)
        orow[c] = f2bf((xr[c] - mu) * inv * g[c] + b[c]);
}

// LayerNorm dual out: fp32 (router, bit-identical routing) + bf16 (GEMM input)
__global__ __launch_bounds__(256) void ln_dual(const float* __restrict__ x,
    const float* __restrict__ g, const float* __restrict__ b,
    float* __restrict__ outF, unsigned short* __restrict__ outBf)
{
    int row = blockIdx.x;
    const float* xr = x + (size_t)row * C_;
    float s = 0.f, ss = 0.f;
    for (int c = threadIdx.x; c < C_; c += 256) { float v = xr[c]; s += v; ss += v * v; }
    __shared__ float S1[256], S2[256];
    S1[threadIdx.x] = s; S2[threadIdx.x] = ss;
    __syncthreads();
    for (int o = 128; o > 0; o >>= 1) {
        if (threadIdx.x < o) { S1[threadIdx.x] += S1[threadIdx.x + o]; S2[threadIdx.x] += S2[threadIdx.x + o]; }
        __syncthreads();
    }
    float mu  = S1[0] * (1.f / C_);
    float var = S2[0] * (1.f / C_) - mu * mu;
    float inv = rsqrtf(var + 1e-6f);
    for (int c = threadIdx.x; c < C_; c += 256) {
        float v = (xr[c] - mu) * inv * g[c] + b[c];
        outF[(size_t)row * C_ + c] = v;
        outBf[(size_t)row * C_ + c] = f2bf(v);
    }
}

// ---------------------------------------------------------------------------
// Dense bf16 MFMA GEMM (async staging, XOR-swizzled unpadded LDS, BK=32).
// out = A[M][K] @ Bt[N][K]^T + bias. 128x128 tile, 4 waves 2x2 of 64x64.
// mode 0: bf16 out[M][N]; mode 1: fp32 out[M][N] +=; mode 4: out = xin + acc+bias
// mode 3: fused KV (N=256): cols<128 -> K natural; cols>=128 -> V transposed
// mode 5: fused QKV (N=768): cols<512 -> Q natural (outBf);
//         512..639 -> K natural (outBf2); 640..767 -> V transposed (outBf3)
// ---------------------------------------------------------------------------
__global__ __launch_bounds__(256) void dense_mfma(
    const unsigned short* __restrict__ Abf,
    const unsigned short* __restrict__ Btbf,
    const float* __restrict__ bias,
    const float* __restrict__ xin,
    float* __restrict__ outF,
    unsigned short* __restrict__ outBf,
    unsigned short* __restrict__ outBf2,
    unsigned short* __restrict__ outBf3,
    int N, int K, int mode, int NkPer)
{
    int row0 = blockIdx.y * 128;
    int col0 = blockIdx.x * 128;

    __shared__ unsigned short As[128 * 32];   // 64B rows, swizzled chunks
    __shared__ unsigned short Bs[128 * 32];

    int tid = threadIdx.x;
    int lane = tid & 63, wid = tid >> 6;
    int lrow = lane >> 2;
    int cswz = (((lane & 3) ^ ((lane >> 3) & 3)) << 3);   // shorts
    int ar0 = 16 * (wid * 2) + lrow;
    int ar1 = ar0 + 16;
    const unsigned short* gA0 = Abf + (size_t)(row0 + ar0) * K + cswz;
    const unsigned short* gA1 = Abf + (size_t)(row0 + ar1) * K + cswz;
    const unsigned short* gB0 = Btbf + (size_t)(col0 + ar0) * K + cswz;
    const unsigned short* gB1 = Btbf + (size_t)(col0 + ar1) * K + cswz;
    unsigned short* lA0 = As + (wid * 2) * 512;
    unsigned short* lA1 = lA0 + 512;
    unsigned short* lB0 = Bs + (wid * 2) * 512;
    unsigned short* lB1 = lB0 + 512;

    int wm0 = (wid & 1) * 64, wn0 = (wid >> 1) * 64;
    int lm = lane & 15, lq = lane >> 4;
    int swb = (lq ^ ((lm >> 1) & 3)) << 3;    // shorts
    int aoff[4], boff[4];
#pragma unroll
    for (int i = 0; i < 4; i++) {
        aoff[i] = (wm0 + 16 * i + lm) * 32 + swb;
        boff[i] = (wn0 + 16 * i + lm) * 32 + swb;
    }

    f32x4 acc[4][4];
#pragma unroll
    for (int i = 0; i < 4; i++)
#pragma unroll
        for (int j = 0; j < 4; j++)
            acc[i][j] = (f32x4){0.f, 0.f, 0.f, 0.f};

    for (int k0 = 0; k0 < K; k0 += 32) {
        __syncthreads();
        gl2lds16(gA0 + k0, lA0);
        gl2lds16(gA1 + k0, lA1);
        gl2lds16(gB0 + k0, lB0);
        gl2lds16(gB1 + k0, lB1);
        __syncthreads();

        bf16x8 av[4], bv[4];
#pragma unroll
        for (int i = 0; i < 4; i++) av[i] = *(const bf16x8*)&As[aoff[i]];
#pragma unroll
        for (int i = 0; i < 4; i++) bv[i] = *(const bf16x8*)&Bs[boff[i]];
#pragma unroll
        for (int mi = 0; mi < 4; mi++)
#pragma unroll
            for (int ni = 0; ni < 4; ni++)
                acc[mi][ni] = __builtin_amdgcn_mfma_f32_16x16x32_bf16(av[mi], bv[ni], acc[mi][ni], 0, 0, 0);
    }

#pragma unroll
    for (int mi = 0; mi < 4; mi++) {
#pragma unroll
        for (int ri = 0; ri < 4; ri++) {
            int gr = row0 + wm0 + 16 * mi + lq * 4 + ri;
            if (mode == 5) {
#pragma unroll
                for (int ni = 0; ni < 4; ni++) {
                    int gc = col0 + wn0 + 16 * ni + lm;
                    float v = acc[mi][ni][ri] + bias[gc];
                    if (gc < 512) {
                        outBf[(size_t)gr * 512 + gc] = f2bf(v);
                    } else if (gc < 640) {
                        outBf2[(size_t)gr * 128 + (gc - 512)] = f2bf(v);
                    } else {
                        int bb = gr / NkPer;
                        int mm = gr - bb * NkPer;
                        outBf3[((size_t)bb * 128 + (gc - 640)) * NkPer + mm] = f2bf(v);
                    }
                }
            } else if (mode == 3) {
#pragma unroll
                for (int ni = 0; ni < 4; ni++) {
                    int gc = col0 + wn0 + 16 * ni + lm;
                    float v = acc[mi][ni][ri] + bias[gc];
                    if (gc < 128) {
                        outBf[(size_t)gr * 128 + gc] = f2bf(v);
                    } else {
                        int bb = gr / NkPer;
                        int mm = gr - bb * NkPer;
                        outBf2[((size_t)bb * 128 + (gc - 128)) * NkPer + mm] = f2bf(v);
                    }
                }
            } else if (mode == 1) {
                size_t orow = (size_t)gr * N;
#pragma unroll
                for (int ni = 0; ni < 4; ni++) {
                    int gc = col0 + wn0 + 16 * ni + lm;
                    outF[orow + gc] += acc[mi][ni][ri] + bias[gc];
                }
            } else if (mode == 4) {
                size_t orow = (size_t)gr * N;
#pragma unroll
                for (int ni = 0; ni < 4; ni++) {
                    int gc = col0 + wn0 + 16 * ni + lm;
                    outF[orow + gc] = xin[orow + gc] + acc[mi][ni][ri] + bias[gc];
                }
            } else {
                size_t orow = (size_t)gr * N;
#pragma unroll
                for (int ni = 0; ni < 4; ni++) {
                    int gc = col0 + wn0 + 16 * ni + lm;
                    outBf[orow + gc] = f2bf(acc[mi][ni][ri] + bias[gc]);
                }
            }
        }
    }
}

// ---------------------------------------------------------------------------
// MFMA flash attention (fixed-shift softmax, split-K) — validated r5-r8.
// gridDim.z = Z chunks; writes fp32 partials (Opart/Lpart); combine normalizes.
// ---------------------------------------------------------------------------
__global__ __launch_bounds__(256) void attn_mfma(
    const unsigned short* __restrict__ Q,
    const unsigned short* __restrict__ K,
    const unsigned short* __restrict__ Vt,
    float* __restrict__ Opart,
    float* __restrict__ Lpart,
    int NkPer, int causal)
{
    __shared__ unsigned short Qs[64 * 72];
    __shared__ unsigned short Ks[64 * 72];
    __shared__ unsigned short Vs[64 * 72];
    unsigned short* Ps = Qs;

    int tid = threadIdx.x;
    int qt = blockIdx.x, bh = blockIdx.y, z = blockIdx.z;
    int b = bh >> 3, h = bh & 7, g = h >> 2;
    int q0 = qt * 64;

#pragma unroll
    for (int i = 0; i < 2; i++) {
        int s = tid + (i << 8);
        int r = s >> 3, c8 = (s & 7) << 3;
        *(uint4*)&Qs[r * 72 + c8] =
            *(const uint4*)&Q[(size_t)(b * N_ + q0 + r) * C_ + h * D_ + c8];
    }
    __syncthreads();

    int lane = tid & 63, wid = tid >> 6;
    int lm = lane & 15, lq = lane >> 4;
    int arow = wid * 16 + lm;

    bf16x8 qf[2];
    qf[0] = *(const bf16x8*)&Qs[arow * 72 + lq * 8];
    qf[1] = *(const bf16x8*)&Qs[arow * 72 + lq * 8 + 32];

    float lsum[4];
    f32x4 of[4];
#pragma unroll
    for (int i = 0; i < 4; i++) { lsum[i] = 0.f; of[i] = (f32x4){0.f,0.f,0.f,0.f}; }

    int nkt = causal ? (qt + 1) : ((NkPer + 63) >> 6);
    int nz = gridDim.z;
    int per = (nkt + nz - 1) / nz;
    int kt0 = z * per;
    int kt1 = min(nkt, kt0 + per);

    for (int kt = kt0; kt < kt1; kt++) {
        int k0 = kt << 6;
        __syncthreads();
#pragma unroll
        for (int i = 0; i < 2; i++) {
            int s = tid + (i << 8);
            int r = s >> 3, c8 = (s & 7) << 3;
            *(uint4*)&Ks[r * 72 + c8] =
                *(const uint4*)&K[(size_t)(b * NkPer + k0 + r) * (KVH_ * D_) + g * D_ + c8];
            *(uint4*)&Vs[r * 72 + c8] =
                *(const uint4*)&Vt[(size_t)(b * (KVH_ * D_) + g * D_ + r) * NkPer + k0 + c8];
        }
        __syncthreads();

        f32x4 sf[4];
#pragma unroll
        for (int i = 0; i < 4; i++) sf[i] = (f32x4){0.f,0.f,0.f,0.f};
#pragma unroll
        for (int ks = 0; ks < 2; ks++) {
#pragma unroll
            for (int ni = 0; ni < 4; ni++) {
                bf16x8 bv = *(const bf16x8*)&Ks[(16 * ni + lm) * 72 + lq * 8 + 32 * ks];
                sf[ni] = __builtin_amdgcn_mfma_f32_16x16x32_bf16(qf[ks], bv, sf[ni], 0, 0, 0);
            }
        }

        bool diag = causal && (k0 + 63 > q0 + wid * 16);
#pragma unroll
        for (int ni = 0; ni < 4; ni++)
#pragma unroll
            for (int ri = 0; ri < 4; ri++) {
                float v = sf[ni][ri] * 0.125f - 8.f;
                if (diag && (k0 + 16 * ni + lm > q0 + wid * 16 + lq * 4 + ri)) v = -1e30f;
                float p = __expf(v);
                sf[ni][ri] = p;
                lsum[ri] += p;
            }

#pragma unroll
        for (int ni = 0; ni < 4; ni++)
#pragma unroll
            for (int ri = 0; ri < 4; ri++)
                Ps[(wid * 16 + lq * 4 + ri) * 72 + 16 * ni + lm] = f2bf(sf[ni][ri]);
        __syncthreads();

        bf16x8 pf0 = *(const bf16x8*)&Ps[arow * 72 + lq * 8];
        bf16x8 pf1 = *(const bf16x8*)&Ps[arow * 72 + lq * 8 + 32];
#pragma unroll
        for (int ni = 0; ni < 4; ni++) {
            bf16x8 vv0 = *(const bf16x8*)&Vs[(16 * ni + lm) * 72 + lq * 8];
            bf16x8 vv1 = *(const bf16x8*)&Vs[(16 * ni + lm) * 72 + lq * 8 + 32];
            of[ni] = __builtin_amdgcn_mfma_f32_16x16x32_bf16(pf0, vv0, of[ni], 0, 0, 0);
            of[ni] = __builtin_amdgcn_mfma_f32_16x16x32_bf16(pf1, vv1, of[ni], 0, 0, 0);
        }
    }

#pragma unroll
    for (int ri = 0; ri < 4; ri++) {
        float s = lsum[ri];
        s += __shfl_xor(s, 1);
        s += __shfl_xor(s, 2);
        s += __shfl_xor(s, 4);
        s += __shfl_xor(s, 8);
        lsum[ri] = s;
    }

    size_t zofs = (size_t)z * BN_ * C_;
#pragma unroll
    for (int ri = 0; ri < 4; ri++) {
        int q = q0 + wid * 16 + lq * 4 + ri;
        size_t orow = zofs + (size_t)(b * N_ + q) * C_ + h * D_;
#pragma unroll
        for (int ni = 0; ni < 4; ni++)
            Opart[orow + 16 * ni + lm] = of[ni][ri];
        if (lm == 0)
            Lpart[(size_t)z * (B_ * H_ * N_) + bh * N_ + q] = lsum[ri];
    }
}

// combine Z split-K chunks: Obf = (sum_z Oz) / (sum_z lz)
__global__ __launch_bounds__(256) void attn_combine(const float* __restrict__ Opart,
    const float* __restrict__ Lpart, unsigned short* __restrict__ Obf, int Z)
{
    int flat = (blockIdx.x * 256 + threadIdx.x) * 4;
    int row = flat >> 9, col = flat & 511;
    int b = row >> 11, q = row & (N_ - 1), h = col >> 6;
    int bh = b * 8 + h;
    float l = 0.f;
    for (int z = 0; z < Z; z++) l += Lpart[(size_t)z * (B_ * H_ * N_) + bh * N_ + q];
    float4 o = {0.f, 0.f, 0.f, 0.f};
    for (int z = 0; z < Z; z++) {
        float4 oz = *(const float4*)&Opart[(size_t)z * BN_ * C_ + flat];
        o.x += oz.x; o.y += oz.y; o.z += oz.z; o.w += oz.w;
    }
    float inv = 1.f / l;
    ushort4 ob;
    ob.x = f2bf(o.x * inv); ob.y = f2bf(o.y * inv);
    ob.z = f2bf(o.z * inv); ob.w = f2bf(o.w * inv);
    *(ushort4*)&Obf[flat] = ob;
}

// ---------------------------------------------------------------------------
// Router (atomic-free logits; reduce with fused offsets via done-counter)
// ---------------------------------------------------------------------------
__global__ __launch_bounds__(256) void router_logits(const float* __restrict__ X,
    const float* __restrict__ RW, const float* __restrict__ RB,
    float* __restrict__ gprobs, int* __restrict__ topi, float* __restrict__ gatesv)
{
    int lane = threadIdx.x & 63;
    int t = blockIdx.x * 4 + (threadIdx.x >> 6);
    const float* xr = X + (size_t)t * C_;
    float p[8] = {};
    for (int i = 0; i < 8; i++) {
        int c = i * 64 + lane;
        float xv = xr[c];
#pragma unroll
        for (int e = 0; e < 8; e++) p[e] = fmaf(xv, RW[c * 8 + e], p[e]);
    }
#pragma unroll
    for (int e = 0; e < 8; e++) {
        float v = p[e];
        v += __shfl_xor(v, 32, 64);
        v += __shfl_xor(v, 16, 64);
        v += __shfl_xor(v, 8, 64);
        v += __shfl_xor(v, 4, 64);
        v += __shfl_xor(v, 2, 64);
        v += __shfl_xor(v, 1, 64);
        p[e] = v;
    }
    if (lane == 0) {
        float logits[8], mx = -1e30f;
        for (int e = 0; e < 8; e++) { logits[e] = p[e] + RB[e]; mx = fmaxf(mx, logits[e]); }
        float pr[8], sum = 0.f;
        for (int e = 0; e < 8; e++) { pr[e] = expf(logits[e] - mx); sum += pr[e]; }
        float inv = 1.f / sum;
        for (int e = 0; e < 8; e++) { pr[e] *= inv; gprobs[t * 8 + e] = pr[e]; }
        int i1 = 0;
        for (int e = 1; e < 8; e++) if (pr[e] > pr[i1]) i1 = e;
        int i2 = (i1 == 0) ? 1 : 0;
        for (int e = 0; e < 8; e++) if (e != i1 && pr[e] > pr[i2]) i2 = e;
        float v1 = pr[i1], v2 = pr[i2], sg = 1.f / (v1 + v2);
        topi[t * 2]     = i1;  topi[t * 2 + 1]   = i2;
        gatesv[t * 2]   = v1 * sg;  gatesv[t * 2 + 1] = v2 * sg;
    }
}

// 16 blocks: 0-7 psum[e]; 8-15 counts; last finisher computes padded offsets.
__global__ __launch_bounds__(256) void router_reduce(const float* __restrict__ gprobs,
    const int* __restrict__ topi, int* __restrict__ ctrl, float* __restrict__ psum)
{
    __shared__ float fs[256];
    __shared__ int   is_[256];
    int bid = blockIdx.x, tid = threadIdx.x;
    if (bid < 8) {
        float s = 0.f;
        for (int t = tid; t < BN_; t += 256) s += gprobs[t * 8 + bid];
        fs[tid] = s; __syncthreads();
        for (int o = 128; o > 0; o >>= 1) { if (tid < o) fs[tid] += fs[tid + o]; __syncthreads(); }
        if (tid == 0) psum[bid] = fs[0];
    } else {
        int e = bid - 8, c = 0;
        for (int i = tid; i < BN_ * 2; i += 256) c += (topi[i] == e);
        is_[tid] = c; __syncthreads();
        for (int o = 128; o > 0; o >>= 1) { if (tid < o) is_[tid] += is_[tid + o]; __syncthreads(); }
        if (tid == 0) ctrl[e] = is_[0];
    }
    if (tid == 0) {
        __threadfence();
        int done = atomicAdd(&ctrl[25], 1);
        if (done == 15) {
            __threadfence();
            int off = 0;
            for (int e = 0; e < 8; e++) {
                ctrl[16 + e] = off;
                off += (ctrl[e] + 127) & ~127;
            }
            ctrl[24] = off;
        }
    }
}

__global__ __launch_bounds__(256) void router_scatter(const int* __restrict__ topi,
    const float* __restrict__ gatesv, int* __restrict__ rowtok,
    int* __restrict__ slotidx, int* __restrict__ ctrl)
{
    __shared__ int lcnt[8];
    __shared__ int lbase[8];
    int tid = threadIdx.x;
    int t = blockIdx.x * 256 + tid;
    if (tid < 8) lcnt[tid] = 0;
    __syncthreads();
    int e0 = topi[t * 2], e1 = topi[t * 2 + 1];
    int p0 = atomicAdd(&lcnt[e0], 1);
    int p1 = atomicAdd(&lcnt[e1], 1);
    __syncthreads();
    if (tid < 8) lbase[tid] = atomicAdd(&ctrl[8 + tid], lcnt[tid]);
    __syncthreads();
    int s0 = ctrl[16 + e0] + lbase[e0] + p0;
    int s1 = ctrl[16 + e1] + lbase[e1] + p1;
    rowtok[s0] = t;
    rowtok[s1] = t;
    slotidx[t * 2]     = s0;
    slotidx[t * 2 + 1] = s1;
}

// ---------------------------------------------------------------------------
// MoE bf16 MFMA GEMM, BK=64, async staging (r8-validated).
// mode 1: A = Xbf gathered by rowtok; out = gelu(acc+b1) -> bf16 [slot][F]
// mode 2: A = Hbuf rows off+...;      out = acc+b2       -> bf16 [slot][C]
// ---------------------------------------------------------------------------
__global__ __launch_bounds__(256) void moe_mfma(
    const unsigned short* __restrict__ Abf,
    const unsigned short* __restrict__ Btbf,
    const float* __restrict__ biasAll,
    unsigned short* __restrict__ outBf,
    const int* __restrict__ rowtok,
    const int* __restrict__ ctrl,
    int N, int K, int mode)
{
    int e = blockIdx.z;
    int cnt = ctrl[e];
    int row0 = blockIdx.y * 128;
    if (row0 >= cnt) return;
    int off = ctrl[16 + e];
    int col0 = blockIdx.x * 128;
    const unsigned short* Bt = Btbf + (size_t)e * N * K;
    const float* bias = biasAll + (size_t)e * N;

    __shared__ unsigned short As[128 * 64];   // 16 KB
    __shared__ unsigned short Bs[128 * 64];   // 16 KB
    __shared__ int toks[128];

    int tid = threadIdx.x;
    if (mode == 1 && tid < 128) {
        int gl = row0 + tid;
        toks[tid] = rowtok[off + (gl < cnt ? gl : 0)];
    }
    __syncthreads();

    int lane = tid & 63, wid = tid >> 6;
    int r8 = lane >> 3;
    size_t asrc[4], bsrc[4];
    unsigned short *adst[4], *bdst[4];
#pragma unroll
    for (int i = 0; i < 4; i++) {
        int rA = wid * 32 + i * 8 + r8;
        int srcc = (((lane & 7) ^ (rA & 7)) << 3);      // shorts
        size_t arow = (mode == 1) ? (size_t)toks[rA] * K
                                  : (size_t)(off + row0 + rA) * K;
        asrc[i] = arow + srcc;
        bsrc[i] = (size_t)(col0 + rA) * K + srcc;
        adst[i] = As + (wid * 32 + i * 8) * 64;
        bdst[i] = Bs + (wid * 32 + i * 8) * 64;
    }

    int wm0 = (wid & 1) * 64, wn0 = (wid >> 1) * 64;
    int lm = lane & 15, lq = lane >> 4;
    int x7 = lm & 7;
    int aoff[4][2], boff[4][2];
#pragma unroll
    for (int i = 0; i < 4; i++) {
#pragma unroll
        for (int ks = 0; ks < 2; ks++) {
            int swz = (((ks << 2) + lq) ^ x7) << 3;
            aoff[i][ks] = (wm0 + 16 * i + lm) * 64 + swz;
            boff[i][ks] = (wn0 + 16 * i + lm) * 64 + swz;
        }
    }

    f32x4 acc[4][4];
#pragma unroll
    for (int i = 0; i < 4; i++)
#pragma unroll
        for (int j = 0; j < 4; j++)
            acc[i][j] = (f32x4){0.f, 0.f, 0.f, 0.f};

    for (int k0 = 0; k0 < K; k0 += 64) {
        __syncthreads();
#pragma unroll
        for (int i = 0; i < 4; i++) {
            gl2lds16(Abf + asrc[i] + k0, adst[i]);
            gl2lds16(Bt  + bsrc[i] + k0, bdst[i]);
        }
        __syncthreads();

#pragma unroll
        for (int ks = 0; ks < 2; ks++) {
            bf16x8 av[4], bv[4];
#pragma unroll
            for (int i = 0; i < 4; i++) av[i] = *(const bf16x8*)&As[aoff[i][ks]];
#pragma unroll
            for (int i = 0; i < 4; i++) bv[i] = *(const bf16x8*)&Bs[boff[i][ks]];
#pragma unroll
            for (int mi = 0; mi < 4; mi++)
#pragma unroll
                for (int ni = 0; ni < 4; ni++)
                    acc[mi][ni] = __builtin_amdgcn_mfma_f32_16x16x32_bf16(av[mi], bv[ni], acc[mi][ni], 0, 0, 0);
        }
    }

#pragma unroll
    for (int mi = 0; mi < 4; mi++) {
#pragma unroll
        for (int ri = 0; ri < 4; ri++) {
            int gl = row0 + wm0 + 16 * mi + lq * 4 + ri;
            size_t orow = (size_t)(off + gl) * N;
            if (mode == 1) {
#pragma unroll
                for (int ni = 0; ni < 4; ni++) {
                    int gc = col0 + wn0 + 16 * ni + lm;
                    float hv = 0.f;
                    if (gl < cnt) {
                        float xv = acc[mi][ni][ri] + bias[gc];
                        float z = 0.7978845608f * xv * fmaf(0.044715f, xv * xv, 1.f);
                        hv = __fdividef(xv, 1.f + __expf(-2.f * z));
                    }
                    outBf[orow + gc] = f2bf(hv);
                }
            } else {
#pragma unroll
                for (int ni = 0; ni < 4; ni++) {
                    int gc = col0 + wn0 + 16 * ni + lm;
                    outBf[orow + gc] = f2bf(acc[mi][ni][ri] + bias[gc]);
                }
            }
        }
    }
}

// combine: out[t][c] += g0*eo[s0][c] + g1*eo[s1][c]; block 0 also writes aux
__global__ __launch_bounds__(256) void moe_combine(const unsigned short* __restrict__ slots,
    const int* __restrict__ slotidx, const float* __restrict__ gatesv,
    const int* __restrict__ ctrl, const float* __restrict__ psum,
    float* __restrict__ out)
{
    int flat = (blockIdx.x * 256 + threadIdx.x) * 4;
    int t = flat >> 9, c = flat & 511;
    int s0 = slotidx[t * 2], s1 = slotidx[t * 2 + 1];
    float g0 = gatesv[t * 2], g1 = gatesv[t * 2 + 1];
    ushort4 a = *(const ushort4*)&slots[(size_t)s0 * C_ + c];
    ushort4 b = *(const ushort4*)&slots[(size_t)s1 * C_ + c];
    float4 o = *(float4*)&out[flat];
    o.x += g0 * bf2f(a.x) + g1 * bf2f(b.x);
    o.y += g0 * bf2f(a.y) + g1 * bf2f(b.y);
    o.z += g0 * bf2f(a.z) + g1 * bf2f(b.z);
    o.w += g0 * bf2f(a.w) + g1 * bf2f(b.w);
    *(float4*)&out[flat] = o;
    if (blockIdx.x == 0 && threadIdx.x == 0) {
        float s = 0.f;
        for (int e = 0; e < 8; e++)
            s += ((float)ctrl[e] / (float)BN_) * (psum[e] / (float)BN_);
        out[(size_t)BN_ * C_] = 8.f * s;
    }
}

// ---------------------------------------------------------------------------
extern "C" void kernel_launch(void* const* d_in, const int* in_sizes, int n_in,
                              void* d_out, int out_size, void* d_ws, size_t ws_size,
                              hipStream_t stream)
{
    const float* x      = (const float*)d_in[0];
    const float* vis    = (const float*)d_in[1];
    const float* ln1g   = (const float*)d_in[2];
    const float* ln1b   = (const float*)d_in[3];
    const float* ln2g   = (const float*)d_in[4];
    const float* ln2b   = (const float*)d_in[5];
    const float* ln3g   = (const float*)d_in[6];
    const float* ln3b   = (const float*)d_in[7];
    const float* sa_wq  = (const float*)d_in[8];
    const float* sa_bq  = (const float*)d_in[9];
    const float* sa_wk  = (const float*)d_in[10];
    const float* sa_bk  = (const float*)d_in[11];
    const float* sa_wv  = (const float*)d_in[12];
    const float* sa_bv  = (const float*)d_in[13];
    const float* sa_wo  = (const float*)d_in[14];
    const float* sa_bo  = (const float*)d_in[15];
    const float* ca_wq  = (const float*)d_in[16];
    const float* ca_bq  = (const float*)d_in[17];
    const float* ca_wk  = (const float*)d_in[18];
    const float* ca_bk  = (const float*)d_in[19];
    const float* ca_wv  = (const float*)d_in[20];
    const float* ca_bv  = (const float*)d_in[21];
    const float* ca_wo  = (const float*)d_in[22];
    const float* ca_bo  = (const float*)d_in[23];
    const float* rw     = (const float*)d_in[24];
    const float* rb     = (const float*)d_in[25];
    const float* e_w1   = (const float*)d_in[26];
    const float* e_b1   = (const float*)d_in[27];
    const float* e_w2   = (const float*)d_in[28];
    const float* e_b2   = (const float*)d_in[29];

    float* out = (float*)d_out;

    char* ws = (char*)d_ws;
    size_t off = 0;
    auto alloc = [&](size_t bytes) -> void* {
        void* p = ws + off;
        off = (off + bytes + 255) & ~(size_t)255;
        return p;
    };
    float* hbuf    = (float*)alloc((size_t)BN_ * C_ * 4);                   // LN3 fp32
    unsigned short* hbz = (unsigned short*)alloc((size_t)BN_ * C_ * 2);     // bf16 LN out
    unsigned short* visbf = (unsigned short*)alloc((size_t)BM_ * C_ * 2);
    // eoslots (bf16 [17408][C] = 17.9 MB) overlays hbuf+hbz, both dead during
    // MoE GEMM2/combine.
    unsigned short* eoslots = (unsigned short*)hbuf;
    // union region: attention temps overlap MoE H buffer; opart Z=3 fits EXACTLY
    char* ureg = (char*)alloc((size_t)17408 * F_ * 2);                       // 71,303,168 B
    unsigned short* moeH = (unsigned short*)ureg;
    unsigned short* qbf  = (unsigned short*)(ureg);                          // 8.4 MB
    unsigned short* obf  = (unsigned short*)(ureg + (size_t)BN_ * C_ * 2);   // 8.4 MB
    unsigned short* kbf  = (unsigned short*)(ureg + (size_t)BN_ * C_ * 4);   // 2.1 MB
    unsigned short* vtbf = (unsigned short*)(ureg + (size_t)BN_ * C_ * 4 + (size_t)BN_ * KVH_ * D_ * 2);
    float* opart = (float*)(ureg + (size_t)BN_ * C_ * 4 + (size_t)BN_ * KVH_ * D_ * 4); // 3 x 16.78 MB
    float* lpart = (float*)alloc((size_t)3 * B_ * H_ * N_ * 4);              // 0.79 MB
    unsigned short* sa_wqt = (unsigned short*)alloc((size_t)C_ * C_ * 2);    // adjacent to
    unsigned short* sa_wkvt = (unsigned short*)alloc((size_t)C_ * 2 * KVH_ * D_ * 2); // -> packed [768][512]
    unsigned short* sa_wot = (unsigned short*)alloc((size_t)C_ * C_ * 2);
    unsigned short* ca_wqt = (unsigned short*)alloc((size_t)C_ * C_ * 2);
    unsigned short* ca_wkvt = (unsigned short*)alloc((size_t)C_ * 2 * KVH_ * D_ * 2);
    unsigned short* ca_wot = (unsigned short*)alloc((size_t)C_ * C_ * 2);
    float* bqkv_sa = (float*)alloc(768 * 4);
    float* bkv_ca  = (float*)alloc(256 * 4);
    unsigned short* w1t  = (unsigned short*)alloc((size_t)E_ * C_ * F_ * 2);
    unsigned short* w2t  = (unsigned short*)alloc((size_t)E_ * F_ * C_ * 2);
    float* gprobs  = (float*)alloc((size_t)BN_ * 8 * 4);
    int*   topi    = (int*)  alloc((size_t)BN_ * 2 * 4);
    float* gatesv  = (float*)alloc((size_t)BN_ * 2 * 4);
    int*   rowtok  = (int*)  alloc(17408 * 4);
    int*   slotidx = (int*)  alloc((size_t)BN_ * 2 * 4);
    int*   ctrl    = (int*)  alloc(256);
    float* psum    = (float*)((char*)ctrl + 128);
    (void)ws_size; (void)in_sizes; (void)n_in; (void)out_size;

    // ---- one-shot prep: all transposes + vis cast + bias packs + ctrl zero ----
    prep_all<<<18817, 256, 0, stream>>>(
        sa_wq, sa_wk, sa_wv, sa_wo, ca_wq, ca_wk, ca_wv, ca_wo,
        e_w1, e_w2, vis, sa_bq, sa_bk, sa_bv, ca_bk, ca_bv,
        sa_wqt, sa_wkvt, sa_wot, ca_wqt, ca_wkvt, ca_wot,
        w1t, w2t, visbf, bqkv_sa, bkv_ca, ctrl);

    // ---- self-attention (fused QKV; residual from x via Wo mode 4) ----
    ln_bf<<<BN_, 256, 0, stream>>>(x, ln1g, ln1b, hbz);
    dense_mfma<<<dim3(6, 64), 256, 0, stream>>>(hbz, sa_wqt, bqkv_sa, nullptr, nullptr,
                                                qbf, kbf, vtbf, 768, C_, 5, N_);
    attn_mfma<<<dim3(N_/64, B_*H_, 3), 256, 0, stream>>>(qbf, kbf, vtbf, opart, lpart, N_, 1);
    attn_combine<<<(BN_*C_)/1024, 256, 0, stream>>>(opart, lpart, obf, 3);
    dense_mfma<<<dim3(4, 64), 256, 0, stream>>>(obf, sa_wot, sa_bo, x, out,
                                                nullptr, nullptr, nullptr, C_, C_, 4, 0);

    // ---- cross-attention ----
    ln_bf<<<BN_, 256, 0, stream>>>(out, ln2g, ln2b, hbz);
    dense_mfma<<<dim3(4, 64), 256, 0, stream>>>(hbz, ca_wqt, ca_bq, nullptr, nullptr,
                                                qbf, nullptr, nullptr, C_, C_, 0, 0);
    dense_mfma<<<dim3(2, 18), 256, 0, stream>>>(visbf, ca_wkvt, bkv_ca, nullptr, nullptr,
                                                kbf, vtbf, nullptr, 256, C_, 3, M_);
    attn_mfma<<<dim3(N_/64, B_*H_, 2), 256, 0, stream>>>(qbf, kbf, vtbf, opart, lpart, M_, 0);
    attn_combine<<<(BN_*C_)/1024, 256, 0, stream>>>(opart, lpart, obf, 2);
    dense_mfma<<<dim3(4, 64), 256, 0, stream>>>(obf, ca_wot, ca_bo, nullptr, out,
                                                nullptr, nullptr, nullptr, C_, C_, 1, 0);

    // ---- MoE ----
    ln_dual<<<BN_, 256, 0, stream>>>(out, ln3g, ln3b, hbuf, hbz);
    router_logits<<<BN_/4, 256, 0, stream>>>(hbuf, rw, rb, gprobs, topi, gatesv);
    router_reduce<<<16, 256, 0, stream>>>(gprobs, topi, ctrl, psum);
    router_scatter<<<BN_/256, 256, 0, stream>>>(topi, gatesv, rowtok, slotidx, ctrl);
    moe_mfma<<<dim3(F_/128, BN_/128, E_), 256, 0, stream>>>(
        hbz, w1t, e_b1, moeH, rowtok, ctrl, F_, C_, 1);
    moe_mfma<<<dim3(C_/128, BN_/128, E_), 256, 0, stream>>>(
        moeH, w2t, e_b2, eoslots, rowtok, ctrl, C_, F_, 2);
    moe_combine<<<(BN_*C_)/1024, 256, 0, stream>>>(eoslots, slotidx, gatesv, ctrl, psum, out);
}

// Round 10
// 646.151 us; speedup vs baseline: 1.1294x; 1.0059x over previous
//
#include <hip/hip_runtime.h>
#include <cstddef>
#include <cstdint>

// Problem constants
#define B_   4
#define N_   2048
#define M_   576
#define C_   512
#define H_   8
#define KVH_ 2
#define D_   64
#define E_   8
#define F_   2048
#define BN_  (B_*N_)    // 8192 tokens
#define BM_  (B_*M_)    // 2304 vision tokens

typedef __attribute__((ext_vector_type(8))) short bf16x8;
typedef __attribute__((ext_vector_type(4))) float f32x4;

__device__ __forceinline__ unsigned short f2bf(float f) {
    union { float f; unsigned int u; } v; v.f = f;
    unsigned int r = v.u + 0x7FFFu + ((v.u >> 16) & 1u);
    return (unsigned short)(r >> 16);
}
__device__ __forceinline__ float bf2f(unsigned short u) {
    union { unsigned int u; float f; } v; v.u = ((unsigned int)u) << 16;
    return v.f;
}

// async global->LDS 16B/lane; LDS dest = wave-uniform base + lane*16
typedef __attribute__((address_space(1))) void glb_void;
typedef __attribute__((address_space(3))) void lds_void;
__device__ __forceinline__ void gl2lds16(const unsigned short* g, unsigned short* l) {
    __builtin_amdgcn_global_load_lds((glb_void*)g, (lds_void*)l, 16, 0, 0);
}

// ---------------------------------------------------------------------------
// prep_all: ALL weight transposes + vis cast + bias packs + ctrl zero in ONE
// launch. sa_wqt/sa_wkvt are adjacent allocations -> packed [768][512] QKV.
// ---------------------------------------------------------------------------
__global__ __launch_bounds__(256) void prep_all(
    const float* __restrict__ sa_wq, const float* __restrict__ sa_wk,
    const float* __restrict__ sa_wv, const float* __restrict__ sa_wo,
    const float* __restrict__ ca_wq, const float* __restrict__ ca_wk,
    const float* __restrict__ ca_wv, const float* __restrict__ ca_wo,
    const float* __restrict__ e_w1, const float* __restrict__ e_w2,
    const float* __restrict__ vis,
    const float* __restrict__ sa_bq,
    const float* __restrict__ sa_bk, const float* __restrict__ sa_bv,
    const float* __restrict__ ca_bk, const float* __restrict__ ca_bv,
    unsigned short* __restrict__ sa_wqt, unsigned short* __restrict__ sa_wkvt,
    unsigned short* __restrict__ sa_wot,
    unsigned short* __restrict__ ca_wqt, unsigned short* __restrict__ ca_wkvt,
    unsigned short* __restrict__ ca_wot,
    unsigned short* __restrict__ w1t, unsigned short* __restrict__ w2t,
    unsigned short* __restrict__ visbf,
    float* __restrict__ bqkv_sa, float* __restrict__ bkv_ca,
    int* __restrict__ ctrl)
{
    __shared__ float T[32][33];
    int t = blockIdx.x;
    int tid = threadIdx.x;

    if (t < 17664) {
        const float* W; unsigned short* Wt; int K, N, kt, nt;
        if (t < 1280) {
            if (t < 256)      { W = sa_wq; Wt = sa_wqt; K = 512; N = 512; int r = t;        nt = r & 15; kt = r >> 4; }
            else if (t < 320) { W = sa_wk; Wt = sa_wkvt;            K = 512; N = 128; int r = t - 256; nt = r & 3;  kt = r >> 2; }
            else if (t < 384) { W = sa_wv; Wt = sa_wkvt + 128*512;  K = 512; N = 128; int r = t - 320; nt = r & 3;  kt = r >> 2; }
            else if (t < 640) { W = sa_wo; Wt = sa_wot; K = 512; N = 512; int r = t - 384;  nt = r & 15; kt = r >> 4; }
            else if (t < 896) { W = ca_wq; Wt = ca_wqt; K = 512; N = 512; int r = t - 640;  nt = r & 15; kt = r >> 4; }
            else if (t < 960) { W = ca_wk; Wt = ca_wkvt;            K = 512; N = 128; int r = t - 896; nt = r & 3;  kt = r >> 2; }
            else if (t < 1024){ W = ca_wv; Wt = ca_wkvt + 128*512;  K = 512; N = 128; int r = t - 960; nt = r & 3;  kt = r >> 2; }
            else              { W = ca_wo; Wt = ca_wot; K = 512; N = 512; int r = t - 1024; nt = r & 15; kt = r >> 4; }
        } else if (t < 9472) {
            int r = t - 1280; int e = r >> 10; r &= 1023;
            W = e_w1 + (size_t)e * C_ * F_; Wt = w1t + (size_t)e * C_ * F_;
            K = C_; N = F_; nt = r & 63; kt = r >> 6;
        } else {
            int r = t - 9472; int e = r >> 10; r &= 1023;
            W = e_w2 + (size_t)e * F_ * C_; Wt = w2t + (size_t)e * F_ * C_;
            K = F_; N = C_; nt = r & 15; kt = r >> 4;
        }
        int rr = tid >> 3, c4 = (tid & 7) * 4;
        int k0 = kt * 32, n0 = nt * 32;
        float4 v = *(const float4*)&W[(size_t)(k0 + rr) * N + n0 + c4];
        T[rr][c4 + 0] = v.x; T[rr][c4 + 1] = v.y; T[rr][c4 + 2] = v.z; T[rr][c4 + 3] = v.w;
        __syncthreads();
        ushort4 o;
        o.x = f2bf(T[c4 + 0][rr]); o.y = f2bf(T[c4 + 1][rr]);
        o.z = f2bf(T[c4 + 2][rr]); o.w = f2bf(T[c4 + 3][rr]);
        *(ushort4*)&Wt[(size_t)(n0 + rr) * K + k0 + c4] = o;
    } else if (t < 18816) {
        int i = (t - 17664) * 1024 + tid * 4;
        float4 v = *(const float4*)(vis + i);
        ushort4 o;
        o.x = f2bf(v.x); o.y = f2bf(v.y); o.z = f2bf(v.z); o.w = f2bf(v.w);
        *(ushort4*)(visbf + i) = o;
    } else {
        // packed bias for fused self-QKV: [bq(512) | bk(128) | bv(128)]
        for (int c = tid; c < 512; c += 256) bqkv_sa[c] = sa_bq[c];
        if (tid < 128) {
            bqkv_sa[512 + tid] = sa_bk[tid];
            bqkv_sa[640 + tid] = sa_bv[tid];
            bkv_ca[tid]        = ca_bk[tid];
            bkv_ca[128 + tid]  = ca_bv[tid];
        }
        if (tid < 32) ctrl[tid] = 0;
    }
}

// ---------------------------------------------------------------------------
// LayerNorm bf16 out (LN1/LN2)
// ---------------------------------------------------------------------------
__global__ __launch_bounds__(256) void ln_bf(const float* __restrict__ x,
    const float* __restrict__ g, const float* __restrict__ b, unsigned short* __restrict__ out)
{
    int row = blockIdx.x;
    const float* xr = x + (size_t)row * C_;
    float s = 0.f, ss = 0.f;
    for (int c = threadIdx.x; c < C_; c += 256) { float v = xr[c]; s += v; ss += v * v; }
    __shared__ float S1[256], S2[256];
    S1[threadIdx.x] = s; S2[threadIdx.x] = ss;
    __syncthreads();
    for (int o = 128; o > 0; o >>= 1) {
        if (threadIdx.x < o) { S1[threadIdx.x] += S1[threadIdx.x + o]; S2[threadIdx.x] += S2[threadIdx.x + o]; }
        __syncthreads();
    }
    float mu  = S1[0] * (1.f / C_);
    float var = S2[0] * (1.f / C_) - mu * mu;
    float inv = rsqrtf(var + 1e-6f);
    unsigned short* orow = out + (size_t)row * C_;
    for (int c = threadIdx.x; c < C_; c += 256)
        orow[c] = f2bf((xr[c] - mu) * inv * g[c] + b[c]);
}

// LayerNorm dual out: fp32 (router, bit-identical routing) + bf16 (GEMM input)
__global__ __launch_bounds__(256) void ln_dual(const float* __restrict__ x,
    const float* __restrict__ g, const float* __restrict__ b,
    float* __restrict__ outF, unsigned short* __restrict__ outBf)
{
    int row = blockIdx.x;
    const float* xr = x + (size_t)row * C_;
    float s = 0.f, ss = 0.f;
    for (int c = threadIdx.x; c < C_; c += 256) { float v = xr[c]; s += v; ss += v * v; }
    __shared__ float S1[256], S2[256];
    S1[threadIdx.x] = s; S2[threadIdx.x] = ss;
    __syncthreads();
    for (int o = 128; o > 0; o >>= 1) {
        if (threadIdx.x < o) { S1[threadIdx.x] += S1[threadIdx.x + o]; S2[threadIdx.x] += S2[threadIdx.x + o]; }
        __syncthreads();
    }
    float mu  = S1[0] * (1.f / C_);
    float var = S2[0] * (1.f / C_) - mu * mu;
    float inv = rsqrtf(var + 1e-6f);
    for (int c = threadIdx.x; c < C_; c += 256) {
        float v = (xr[c] - mu) * inv * g[c] + b[c];
        outF[(size_t)row * C_ + c] = v;
        outBf[(size_t)row * C_ + c] = f2bf(v);
    }
}

// ---------------------------------------------------------------------------
// Dense bf16 MFMA GEMM (async staging, XOR-swizzled unpadded LDS, BK=32).
// out = A[M][K] @ Bt[N][K]^T + bias. 128x128 tile, 4 waves 2x2 of 64x64.
// mode 0: bf16 out[M][N]; mode 1: fp32 out[M][N] +=; mode 4: out = xin + acc+bias
// mode 3: fused KV (N=256): cols<128 -> K natural; cols>=128 -> V transposed
// mode 5: fused QKV (N=768): cols<512 -> Q natural (outBf);
//         512..639 -> K natural (outBf2); 640..767 -> V transposed (outBf3)
// ---------------------------------------------------------------------------
__global__ __launch_bounds__(256) void dense_mfma(
    const unsigned short* __restrict__ Abf,
    const unsigned short* __restrict__ Btbf,
    const float* __restrict__ bias,
    const float* __restrict__ xin,
    float* __restrict__ outF,
    unsigned short* __restrict__ outBf,
    unsigned short* __restrict__ outBf2,
    unsigned short* __restrict__ outBf3,
    int N, int K, int mode, int NkPer)
{
    int row0 = blockIdx.y * 128;
    int col0 = blockIdx.x * 128;

    __shared__ unsigned short As[128 * 32];   // 64B rows, swizzled chunks
    __shared__ unsigned short Bs[128 * 32];

    int tid = threadIdx.x;
    int lane = tid & 63, wid = tid >> 6;
    int lrow = lane >> 2;
    int cswz = (((lane & 3) ^ ((lane >> 3) & 3)) << 3);   // shorts
    int ar0 = 16 * (wid * 2) + lrow;
    int ar1 = ar0 + 16;
    const unsigned short* gA0 = Abf + (size_t)(row0 + ar0) * K + cswz;
    const unsigned short* gA1 = Abf + (size_t)(row0 + ar1) * K + cswz;
    const unsigned short* gB0 = Btbf + (size_t)(col0 + ar0) * K + cswz;
    const unsigned short* gB1 = Btbf + (size_t)(col0 + ar1) * K + cswz;
    unsigned short* lA0 = As + (wid * 2) * 512;
    unsigned short* lA1 = lA0 + 512;
    unsigned short* lB0 = Bs + (wid * 2) * 512;
    unsigned short* lB1 = lB0 + 512;

    int wm0 = (wid & 1) * 64, wn0 = (wid >> 1) * 64;
    int lm = lane & 15, lq = lane >> 4;
    int swb = (lq ^ ((lm >> 1) & 3)) << 3;    // shorts
    int aoff[4], boff[4];
#pragma unroll
    for (int i = 0; i < 4; i++) {
        aoff[i] = (wm0 + 16 * i + lm) * 32 + swb;
        boff[i] = (wn0 + 16 * i + lm) * 32 + swb;
    }

    f32x4 acc[4][4];
#pragma unroll
    for (int i = 0; i < 4; i++)
#pragma unroll
        for (int j = 0; j < 4; j++)
            acc[i][j] = (f32x4){0.f, 0.f, 0.f, 0.f};

    for (int k0 = 0; k0 < K; k0 += 32) {
        __syncthreads();
        gl2lds16(gA0 + k0, lA0);
        gl2lds16(gA1 + k0, lA1);
        gl2lds16(gB0 + k0, lB0);
        gl2lds16(gB1 + k0, lB1);
        __syncthreads();

        bf16x8 av[4], bv[4];
#pragma unroll
        for (int i = 0; i < 4; i++) av[i] = *(const bf16x8*)&As[aoff[i]];
#pragma unroll
        for (int i = 0; i < 4; i++) bv[i] = *(const bf16x8*)&Bs[boff[i]];
#pragma unroll
        for (int mi = 0; mi < 4; mi++)
#pragma unroll
            for (int ni = 0; ni < 4; ni++)
                acc[mi][ni] = __builtin_amdgcn_mfma_f32_16x16x32_bf16(av[mi], bv[ni], acc[mi][ni], 0, 0, 0);
    }

#pragma unroll
    for (int mi = 0; mi < 4; mi++) {
#pragma unroll
        for (int ri = 0; ri < 4; ri++) {
            int gr = row0 + wm0 + 16 * mi + lq * 4 + ri;
            if (mode == 5) {
#pragma unroll
                for (int ni = 0; ni < 4; ni++) {
                    int gc = col0 + wn0 + 16 * ni + lm;
                    float v = acc[mi][ni][ri] + bias[gc];
                    if (gc < 512) {
                        outBf[(size_t)gr * 512 + gc] = f2bf(v);
                    } else if (gc < 640) {
                        outBf2[(size_t)gr * 128 + (gc - 512)] = f2bf(v);
                    } else {
                        int bb = gr / NkPer;
                        int mm = gr - bb * NkPer;
                        outBf3[((size_t)bb * 128 + (gc - 640)) * NkPer + mm] = f2bf(v);
                    }
                }
            } else if (mode == 3) {
#pragma unroll
                for (int ni = 0; ni < 4; ni++) {
                    int gc = col0 + wn0 + 16 * ni + lm;
                    float v = acc[mi][ni][ri] + bias[gc];
                    if (gc < 128) {
                        outBf[(size_t)gr * 128 + gc] = f2bf(v);
                    } else {
                        int bb = gr / NkPer;
                        int mm = gr - bb * NkPer;
                        outBf2[((size_t)bb * 128 + (gc - 128)) * NkPer + mm] = f2bf(v);
                    }
                }
            } else if (mode == 1) {
                size_t orow = (size_t)gr * N;
#pragma unroll
                for (int ni = 0; ni < 4; ni++) {
                    int gc = col0 + wn0 + 16 * ni + lm;
                    outF[orow + gc] += acc[mi][ni][ri] + bias[gc];
                }
            } else if (mode == 4) {
                size_t orow = (size_t)gr * N;
#pragma unroll
                for (int ni = 0; ni < 4; ni++) {
                    int gc = col0 + wn0 + 16 * ni + lm;
                    outF[orow + gc] = xin[orow + gc] + acc[mi][ni][ri] + bias[gc];
                }
            } else {
                size_t orow = (size_t)gr * N;
#pragma unroll
                for (int ni = 0; ni < 4; ni++) {
                    int gc = col0 + wn0 + 16 * ni + lm;
                    outBf[orow + gc] = f2bf(acc[mi][ni][ri] + bias[gc]);
                }
            }
        }
    }
}

// ---------------------------------------------------------------------------
// MFMA flash attention (fixed-shift softmax, split-K). The P LDS round-trip
// is WAVE-PRIVATE (wave wid writes/reads only rows wid*16..wid*16+15), so no
// barrier is needed between P-store and P-load: 2 barriers/tile instead of 3.
// ---------------------------------------------------------------------------
__global__ __launch_bounds__(256) void attn_mfma(
    const unsigned short* __restrict__ Q,
    const unsigned short* __restrict__ K,
    const unsigned short* __restrict__ Vt,
    float* __restrict__ Opart,
    float* __restrict__ Lpart,
    int NkPer, int causal)
{
    __shared__ unsigned short Qs[64 * 72];
    __shared__ unsigned short Ks[64 * 72];
    __shared__ unsigned short Vs[64 * 72];
    unsigned short* Ps = Qs;

    int tid = threadIdx.x;
    int qt = blockIdx.x, bh = blockIdx.y, z = blockIdx.z;
    int b = bh >> 3, h = bh & 7, g = h >> 2;
    int q0 = qt * 64;

#pragma unroll
    for (int i = 0; i < 2; i++) {
        int s = tid + (i << 8);
        int r = s >> 3, c8 = (s & 7) << 3;
        *(uint4*)&Qs[r * 72 + c8] =
            *(const uint4*)&Q[(size_t)(b * N_ + q0 + r) * C_ + h * D_ + c8];
    }
    __syncthreads();

    int lane = tid & 63, wid = tid >> 6;
    int lm = lane & 15, lq = lane >> 4;
    int arow = wid * 16 + lm;

    bf16x8 qf[2];
    qf[0] = *(const bf16x8*)&Qs[arow * 72 + lq * 8];
    qf[1] = *(const bf16x8*)&Qs[arow * 72 + lq * 8 + 32];

    float lsum[4];
    f32x4 of[4];
#pragma unroll
    for (int i = 0; i < 4; i++) { lsum[i] = 0.f; of[i] = (f32x4){0.f,0.f,0.f,0.f}; }

    int nkt = causal ? (qt + 1) : ((NkPer + 63) >> 6);
    int nz = gridDim.z;
    int per = (nkt + nz - 1) / nz;
    int kt0 = z * per;
    int kt1 = min(nkt, kt0 + per);

    for (int kt = kt0; kt < kt1; kt++) {
        int k0 = kt << 6;
        __syncthreads();   // prior readers of Ks/Vs done
#pragma unroll
        for (int i = 0; i < 2; i++) {
            int s = tid + (i << 8);
            int r = s >> 3, c8 = (s & 7) << 3;
            *(uint4*)&Ks[r * 72 + c8] =
                *(const uint4*)&K[(size_t)(b * NkPer + k0 + r) * (KVH_ * D_) + g * D_ + c8];
            *(uint4*)&Vs[r * 72 + c8] =
                *(const uint4*)&Vt[(size_t)(b * (KVH_ * D_) + g * D_ + r) * NkPer + k0 + c8];
        }
        __syncthreads();

        f32x4 sf[4];
#pragma unroll
        for (int i = 0; i < 4; i++) sf[i] = (f32x4){0.f,0.f,0.f,0.f};
#pragma unroll
        for (int ks = 0; ks < 2; ks++) {
#pragma unroll
            for (int ni = 0; ni < 4; ni++) {
                bf16x8 bv = *(const bf16x8*)&Ks[(16 * ni + lm) * 72 + lq * 8 + 32 * ks];
                sf[ni] = __builtin_amdgcn_mfma_f32_16x16x32_bf16(qf[ks], bv, sf[ni], 0, 0, 0);
            }
        }

        bool diag = causal && (k0 + 63 > q0 + wid * 16);
#pragma unroll
        for (int ni = 0; ni < 4; ni++)
#pragma unroll
            for (int ri = 0; ri < 4; ri++) {
                float v = sf[ni][ri] * 0.125f - 8.f;
                if (diag && (k0 + 16 * ni + lm > q0 + wid * 16 + lq * 4 + ri)) v = -1e30f;
                float p = __expf(v);
                sf[ni][ri] = p;
                lsum[ri] += p;
            }

        // P (C-layout) -> wave-private LDS rows -> A-layout; no barrier needed
#pragma unroll
        for (int ni = 0; ni < 4; ni++)
#pragma unroll
            for (int ri = 0; ri < 4; ri++)
                Ps[(wid * 16 + lq * 4 + ri) * 72 + 16 * ni + lm] = f2bf(sf[ni][ri]);

        bf16x8 pf0 = *(const bf16x8*)&Ps[arow * 72 + lq * 8];
        bf16x8 pf1 = *(const bf16x8*)&Ps[arow * 72 + lq * 8 + 32];
#pragma unroll
        for (int ni = 0; ni < 4; ni++) {
            bf16x8 vv0 = *(const bf16x8*)&Vs[(16 * ni + lm) * 72 + lq * 8];
            bf16x8 vv1 = *(const bf16x8*)&Vs[(16 * ni + lm) * 72 + lq * 8 + 32];
            of[ni] = __builtin_amdgcn_mfma_f32_16x16x32_bf16(pf0, vv0, of[ni], 0, 0, 0);
            of[ni] = __builtin_amdgcn_mfma_f32_16x16x32_bf16(pf1, vv1, of[ni], 0, 0, 0);
        }
    }

#pragma unroll
    for (int ri = 0; ri < 4; ri++) {
        float s = lsum[ri];
        s += __shfl_xor(s, 1);
        s += __shfl_xor(s, 2);
        s += __shfl_xor(s, 4);
        s += __shfl_xor(s, 8);
        lsum[ri] = s;
    }

    size_t zofs = (size_t)z * BN_ * C_;
#pragma unroll
    for (int ri = 0; ri < 4; ri++) {
        int q = q0 + wid * 16 + lq * 4 + ri;
        size_t orow = zofs + (size_t)(b * N_ + q) * C_ + h * D_;
#pragma unroll
        for (int ni = 0; ni < 4; ni++)
            Opart[orow + 16 * ni + lm] = of[ni][ri];
        if (lm == 0)
            Lpart[(size_t)z * (B_ * H_ * N_) + bh * N_ + q] = lsum[ri];
    }
}

// combine Z split-K chunks: Obf = (sum_z Oz) / (sum_z lz)
__global__ __launch_bounds__(256) void attn_combine(const float* __restrict__ Opart,
    const float* __restrict__ Lpart, unsigned short* __restrict__ Obf, int Z)
{
    int flat = (blockIdx.x * 256 + threadIdx.x) * 4;
    int row = flat >> 9, col = flat & 511;
    int b = row >> 11, q = row & (N_ - 1), h = col >> 6;
    int bh = b * 8 + h;
    float l = 0.f;
    for (int z = 0; z < Z; z++) l += Lpart[(size_t)z * (B_ * H_ * N_) + bh * N_ + q];
    float4 o = {0.f, 0.f, 0.f, 0.f};
    for (int z = 0; z < Z; z++) {
        float4 oz = *(const float4*)&Opart[(size_t)z * BN_ * C_ + flat];
        o.x += oz.x; o.y += oz.y; o.z += oz.z; o.w += oz.w;
    }
    float inv = 1.f / l;
    ushort4 ob;
    ob.x = f2bf(o.x * inv); ob.y = f2bf(o.y * inv);
    ob.z = f2bf(o.z * inv); ob.w = f2bf(o.w * inv);
    *(ushort4*)&Obf[flat] = ob;
}

// ---------------------------------------------------------------------------
// Router (atomic-free logits; reduce with fused offsets via done-counter)
// ---------------------------------------------------------------------------
__global__ __launch_bounds__(256) void router_logits(const float* __restrict__ X,
    const float* __restrict__ RW, const float* __restrict__ RB,
    float* __restrict__ gprobs, int* __restrict__ topi, float* __restrict__ gatesv)
{
    int lane = threadIdx.x & 63;
    int t = blockIdx.x * 4 + (threadIdx.x >> 6);
    const float* xr = X + (size_t)t * C_;
    float p[8] = {};
    for (int i = 0; i < 8; i++) {
        int c = i * 64 + lane;
        float xv = xr[c];
#pragma unroll
        for (int e = 0; e < 8; e++) p[e] = fmaf(xv, RW[c * 8 + e], p[e]);
    }
#pragma unroll
    for (int e = 0; e < 8; e++) {
        float v = p[e];
        v += __shfl_xor(v, 32, 64);
        v += __shfl_xor(v, 16, 64);
        v += __shfl_xor(v, 8, 64);
        v += __shfl_xor(v, 4, 64);
        v += __shfl_xor(v, 2, 64);
        v += __shfl_xor(v, 1, 64);
        p[e] = v;
    }
    if (lane == 0) {
        float logits[8], mx = -1e30f;
        for (int e = 0; e < 8; e++) { logits[e] = p[e] + RB[e]; mx = fmaxf(mx, logits[e]); }
        float pr[8], sum = 0.f;
        for (int e = 0; e < 8; e++) { pr[e] = expf(logits[e] - mx); sum += pr[e]; }
        float inv = 1.f / sum;
        for (int e = 0; e < 8; e++) { pr[e] *= inv; gprobs[t * 8 + e] = pr[e]; }
        int i1 = 0;
        for (int e = 1; e < 8; e++) if (pr[e] > pr[i1]) i1 = e;
        int i2 = (i1 == 0) ? 1 : 0;
        for (int e = 0; e < 8; e++) if (e != i1 && pr[e] > pr[i2]) i2 = e;
        float v1 = pr[i1], v2 = pr[i2], sg = 1.f / (v1 + v2);
        topi[t * 2]     = i1;  topi[t * 2 + 1]   = i2;
        gatesv[t * 2]   = v1 * sg;  gatesv[t * 2 + 1] = v2 * sg;
    }
}

// 16 blocks: 0-7 psum[e]; 8-15 counts; last finisher computes padded offsets.
__global__ __launch_bounds__(256) void router_reduce(const float* __restrict__ gprobs,
    const int* __restrict__ topi, int* __restrict__ ctrl, float* __restrict__ psum)
{
    __shared__ float fs[256];
    __shared__ int   is_[256];
    int bid = blockIdx.x, tid = threadIdx.x;
    if (bid < 8) {
        float s = 0.f;
        for (int t = tid; t < BN_; t += 256) s += gprobs[t * 8 + bid];
        fs[tid] = s; __syncthreads();
        for (int o = 128; o > 0; o >>= 1) { if (tid < o) fs[tid] += fs[tid + o]; __syncthreads(); }
        if (tid == 0) psum[bid] = fs[0];
    } else {
        int e = bid - 8, c = 0;
        for (int i = tid; i < BN_ * 2; i += 256) c += (topi[i] == e);
        is_[tid] = c; __syncthreads();
        for (int o = 128; o > 0; o >>= 1) { if (tid < o) is_[tid] += is_[tid + o]; __syncthreads(); }
        if (tid == 0) ctrl[e] = is_[0];
    }
    if (tid == 0) {
        __threadfence();
        int done = atomicAdd(&ctrl[25], 1);
        if (done == 15) {
            __threadfence();
            int off = 0;
            for (int e = 0; e < 8; e++) {
                ctrl[16 + e] = off;
                off += (ctrl[e] + 127) & ~127;
            }
            ctrl[24] = off;
        }
    }
}

__global__ __launch_bounds__(256) void router_scatter(const int* __restrict__ topi,
    const float* __restrict__ gatesv, int* __restrict__ rowtok,
    int* __restrict__ slotidx, int* __restrict__ ctrl)
{
    __shared__ int lcnt[8];
    __shared__ int lbase[8];
    int tid = threadIdx.x;
    int t = blockIdx.x * 256 + tid;
    if (tid < 8) lcnt[tid] = 0;
    __syncthreads();
    int e0 = topi[t * 2], e1 = topi[t * 2 + 1];
    int p0 = atomicAdd(&lcnt[e0], 1);
    int p1 = atomicAdd(&lcnt[e1], 1);
    __syncthreads();
    if (tid < 8) lbase[tid] = atomicAdd(&ctrl[8 + tid], lcnt[tid]);
    __syncthreads();
    int s0 = ctrl[16 + e0] + lbase[e0] + p0;
    int s1 = ctrl[16 + e1] + lbase[e1] + p1;
    rowtok[s0] = t;
    rowtok[s1] = t;
    slotidx[t * 2]     = s0;
    slotidx[t * 2 + 1] = s1;
}

// ---------------------------------------------------------------------------
// MoE bf16 MFMA GEMM, BK=64, async staging. __launch_bounds__(256, 4) caps
// registers at 128 (64 VGPR + 64 AGPR acc) -> 4 blocks/CU (was 3, reg-bound).
// mode 1: A = Xbf gathered by rowtok; out = gelu(acc+b1) -> bf16 [slot][F]
// mode 2: A = Hbuf rows off+...;      out = acc+b2       -> bf16 [slot][C]
// ---------------------------------------------------------------------------
__global__ __launch_bounds__(256, 4) void moe_mfma(
    const unsigned short* __restrict__ Abf,
    const unsigned short* __restrict__ Btbf,
    const float* __restrict__ biasAll,
    unsigned short* __restrict__ outBf,
    const int* __restrict__ rowtok,
    const int* __restrict__ ctrl,
    int N, int K, int mode)
{
    int e = blockIdx.z;
    int cnt = ctrl[e];
    int row0 = blockIdx.y * 128;
    if (row0 >= cnt) return;
    int off = ctrl[16 + e];
    int col0 = blockIdx.x * 128;
    const unsigned short* Bt = Btbf + (size_t)e * N * K;
    const float* bias = biasAll + (size_t)e * N;

    __shared__ unsigned short As[128 * 64];   // 16 KB
    __shared__ unsigned short Bs[128 * 64];   // 16 KB
    __shared__ int toks[128];

    int tid = threadIdx.x;
    if (mode == 1 && tid < 128) {
        int gl = row0 + tid;
        toks[tid] = rowtok[off + (gl < cnt ? gl : 0)];
    }
    __syncthreads();

    int lane = tid & 63, wid = tid >> 6;
    int r8 = lane >> 3;
    size_t asrc[4], bsrc[4];
    unsigned short *adst[4], *bdst[4];
#pragma unroll
    for (int i = 0; i < 4; i++) {
        int rA = wid * 32 + i * 8 + r8;
        int srcc = (((lane & 7) ^ (rA & 7)) << 3);      // shorts
        size_t arow = (mode == 1) ? (size_t)toks[rA] * K
                                  : (size_t)(off + row0 + rA) * K;
        asrc[i] = arow + srcc;
        bsrc[i] = (size_t)(col0 + rA) * K + srcc;
        adst[i] = As + (wid * 32 + i * 8) * 64;
        bdst[i] = Bs + (wid * 32 + i * 8) * 64;
    }

    int wm0 = (wid & 1) * 64, wn0 = (wid >> 1) * 64;
    int lm = lane & 15, lq = lane >> 4;
    int x7 = lm & 7;
    int aoff[4][2], boff[4][2];
#pragma unroll
    for (int i = 0; i < 4; i++) {
#pragma unroll
        for (int ks = 0; ks < 2; ks++) {
            int swz = (((ks << 2) + lq) ^ x7) << 3;
            aoff[i][ks] = (wm0 + 16 * i + lm) * 64 + swz;
            boff[i][ks] = (wn0 + 16 * i + lm) * 64 + swz;
        }
    }

    f32x4 acc[4][4];
#pragma unroll
    for (int i = 0; i < 4; i++)
#pragma unroll
        for (int j = 0; j < 4; j++)
            acc[i][j] = (f32x4){0.f, 0.f, 0.f, 0.f};

    for (int k0 = 0; k0 < K; k0 += 64) {
        __syncthreads();
#pragma unroll
        for (int i = 0; i < 4; i++) {
            gl2lds16(Abf + asrc[i] + k0, adst[i]);
            gl2lds16(Bt  + bsrc[i] + k0, bdst[i]);
        }
        __syncthreads();

#pragma unroll
        for (int ks = 0; ks < 2; ks++) {
            bf16x8 av[4], bv[4];
#pragma unroll
            for (int i = 0; i < 4; i++) av[i] = *(const bf16x8*)&As[aoff[i][ks]];
#pragma unroll
            for (int i = 0; i < 4; i++) bv[i] = *(const bf16x8*)&Bs[boff[i][ks]];
#pragma unroll
            for (int mi = 0; mi < 4; mi++)
#pragma unroll
                for (int ni = 0; ni < 4; ni++)
                    acc[mi][ni] = __builtin_amdgcn_mfma_f32_16x16x32_bf16(av[mi], bv[ni], acc[mi][ni], 0, 0, 0);
        }
    }

#pragma unroll
    for (int mi = 0; mi < 4; mi++) {
#pragma unroll
        for (int ri = 0; ri < 4; ri++) {
            int gl = row0 + wm0 + 16 * mi + lq * 4 + ri;
            size_t orow = (size_t)(off + gl) * N;
            if (mode == 1) {
#pragma unroll
                for (int ni = 0; ni < 4; ni++) {
                    int gc = col0 + wn0 + 16 * ni + lm;
                    float hv = 0.f;
                    if (gl < cnt) {
                        float xv = acc[mi][ni][ri] + bias[gc];
                        float z = 0.7978845608f * xv * fmaf(0.044715f, xv * xv, 1.f);
                        hv = __fdividef(xv, 1.f + __expf(-2.f * z));
                    }
                    outBf[orow + gc] = f2bf(hv);
                }
            } else {
#pragma unroll
                for (int ni = 0; ni < 4; ni++) {
                    int gc = col0 + wn0 + 16 * ni + lm;
                    outBf[orow + gc] = f2bf(acc[mi][ni][ri] + bias[gc]);
                }
            }
        }
    }
}

// combine: out[t][c] += g0*eo[s0][c] + g1*eo[s1][c]; block 0 also writes aux
__global__ __launch_bounds__(256) void moe_combine(const unsigned short* __restrict__ slots,
    const int* __restrict__ slotidx, const float* __restrict__ gatesv,
    const int* __restrict__ ctrl, const float* __restrict__ psum,
    float* __restrict__ out)
{
    int flat = (blockIdx.x * 256 + threadIdx.x) * 4;
    int t = flat >> 9, c = flat & 511;
    int s0 = slotidx[t * 2], s1 = slotidx[t * 2 + 1];
    float g0 = gatesv[t * 2], g1 = gatesv[t * 2 + 1];
    ushort4 a = *(const ushort4*)&slots[(size_t)s0 * C_ + c];
    ushort4 b = *(const ushort4*)&slots[(size_t)s1 * C_ + c];
    float4 o = *(float4*)&out[flat];
    o.x += g0 * bf2f(a.x) + g1 * bf2f(b.x);
    o.y += g0 * bf2f(a.y) + g1 * bf2f(b.y);
    o.z += g0 * bf2f(a.z) + g1 * bf2f(b.z);
    o.w += g0 * bf2f(a.w) + g1 * bf2f(b.w);
    *(float4*)&out[flat] = o;
    if (blockIdx.x == 0 && threadIdx.x == 0) {
        float s = 0.f;
        for (int e = 0; e < 8; e++)
            s += ((float)ctrl[e] / (float)BN_) * (psum[e] / (float)BN_);
        out[(size_t)BN_ * C_] = 8.f * s;
    }
}

// ---------------------------------------------------------------------------
extern "C" void kernel_launch(void* const* d_in, const int* in_sizes, int n_in,
                              void* d_out, int out_size, void* d_ws, size_t ws_size,
                              hipStream_t stream)
{
    const float* x      = (const float*)d_in[0];
    const float* vis    = (const float*)d_in[1];
    const float* ln1g   = (const float*)d_in[2];
    const float* ln1b   = (const float*)d_in[3];
    const float* ln2g   = (const float*)d_in[4];
    const float* ln2b   = (const float*)d_in[5];
    const float* ln3g   = (const float*)d_in[6];
    const float* ln3b   = (const float*)d_in[7];
    const float* sa_wq  = (const float*)d_in[8];
    const float* sa_bq  = (const float*)d_in[9];
    const float* sa_wk  = (const float*)d_in[10];
    const float* sa_bk  = (const float*)d_in[11];
    const float* sa_wv  = (const float*)d_in[12];
    const float* sa_bv  = (const float*)d_in[13];
    const float* sa_wo  = (const float*)d_in[14];
    const float* sa_bo  = (const float*)d_in[15];
    const float* ca_wq  = (const float*)d_in[16];
    const float* ca_bq  = (const float*)d_in[17];
    const float* ca_wk  = (const float*)d_in[18];
    const float* ca_bk  = (const float*)d_in[19];
    const float* ca_wv  = (const float*)d_in[20];
    const float* ca_bv  = (const float*)d_in[21];
    const float* ca_wo  = (const float*)d_in[22];
    const float* ca_bo  = (const float*)d_in[23];
    const float* rw     = (const float*)d_in[24];
    const float* rb     = (const float*)d_in[25];
    const float* e_w1   = (const float*)d_in[26];
    const float* e_b1   = (const float*)d_in[27];
    const float* e_w2   = (const float*)d_in[28];
    const float* e_b2   = (const float*)d_in[29];

    float* out = (float*)d_out;

    char* ws = (char*)d_ws;
    size_t off = 0;
    auto alloc = [&](size_t bytes) -> void* {
        void* p = ws + off;
        off = (off + bytes + 255) & ~(size_t)255;
        return p;
    };
    float* hbuf    = (float*)alloc((size_t)BN_ * C_ * 4);                   // LN3 fp32
    unsigned short* hbz = (unsigned short*)alloc((size_t)BN_ * C_ * 2);     // bf16 LN out
    unsigned short* visbf = (unsigned short*)alloc((size_t)BM_ * C_ * 2);
    // eoslots (bf16 [17408][C] = 17.9 MB) overlays hbuf+hbz, both dead during
    // MoE GEMM2/combine.
    unsigned short* eoslots = (unsigned short*)hbuf;
    // union region: attention temps overlap MoE H buffer; opart Z=3 fits EXACTLY
    char* ureg = (char*)alloc((size_t)17408 * F_ * 2);                       // 71,303,168 B
    unsigned short* moeH = (unsigned short*)ureg;
    unsigned short* qbf  = (unsigned short*)(ureg);                          // 8.4 MB
    unsigned short* obf  = (unsigned short*)(ureg + (size_t)BN_ * C_ * 2);   // 8.4 MB
    unsigned short* kbf  = (unsigned short*)(ureg + (size_t)BN_ * C_ * 4);   // 2.1 MB
    unsigned short* vtbf = (unsigned short*)(ureg + (size_t)BN_ * C_ * 4 + (size_t)BN_ * KVH_ * D_ * 2);
    float* opart = (float*)(ureg + (size_t)BN_ * C_ * 4 + (size_t)BN_ * KVH_ * D_ * 4); // 3 x 16.78 MB
    float* lpart = (float*)alloc((size_t)3 * B_ * H_ * N_ * 4);              // 0.79 MB
    unsigned short* sa_wqt = (unsigned short*)alloc((size_t)C_ * C_ * 2);    // adjacent to
    unsigned short* sa_wkvt = (unsigned short*)alloc((size_t)C_ * 2 * KVH_ * D_ * 2); // -> packed [768][512]
    unsigned short* sa_wot = (unsigned short*)alloc((size_t)C_ * C_ * 2);
    unsigned short* ca_wqt = (unsigned short*)alloc((size_t)C_ * C_ * 2);
    unsigned short* ca_wkvt = (unsigned short*)alloc((size_t)C_ * 2 * KVH_ * D_ * 2);
    unsigned short* ca_wot = (unsigned short*)alloc((size_t)C_ * C_ * 2);
    float* bqkv_sa = (float*)alloc(768 * 4);
    float* bkv_ca  = (float*)alloc(256 * 4);
    unsigned short* w1t  = (unsigned short*)alloc((size_t)E_ * C_ * F_ * 2);
    unsigned short* w2t  = (unsigned short*)alloc((size_t)E_ * F_ * C_ * 2);
    float* gprobs  = (float*)alloc((size_t)BN_ * 8 * 4);
    int*   topi    = (int*)  alloc((size_t)BN_ * 2 * 4);
    float* gatesv  = (float*)alloc((size_t)BN_ * 2 * 4);
    int*   rowtok  = (int*)  alloc(17408 * 4);
    int*   slotidx = (int*)  alloc((size_t)BN_ * 2 * 4);
    int*   ctrl    = (int*)  alloc(256);
    float* psum    = (float*)((char*)ctrl + 128);
    (void)ws_size; (void)in_sizes; (void)n_in; (void)out_size;

    // ---- one-shot prep: all transposes + vis cast + bias packs + ctrl zero ----
    prep_all<<<18817, 256, 0, stream>>>(
        sa_wq, sa_wk, sa_wv, sa_wo, ca_wq, ca_wk, ca_wv, ca_wo,
        e_w1, e_w2, vis, sa_bq, sa_bk, sa_bv, ca_bk, ca_bv,
        sa_wqt, sa_wkvt, sa_wot, ca_wqt, ca_wkvt, ca_wot,
        w1t, w2t, visbf, bqkv_sa, bkv_ca, ctrl);

    // ---- self-attention (fused QKV; residual from x via Wo mode 4) ----
    ln_bf<<<BN_, 256, 0, stream>>>(x, ln1g, ln1b, hbz);
    dense_mfma<<<dim3(6, 64), 256, 0, stream>>>(hbz, sa_wqt, bqkv_sa, nullptr, nullptr,
                                                qbf, kbf, vtbf, 768, C_, 5, N_);
    attn_mfma<<<dim3(N_/64, B_*H_, 3), 256, 0, stream>>>(qbf, kbf, vtbf, opart, lpart, N_, 1);
    attn_combine<<<(BN_*C_)/1024, 256, 0, stream>>>(opart, lpart, obf, 3);
    dense_mfma<<<dim3(4, 64), 256, 0, stream>>>(obf, sa_wot, sa_bo, x, out,
                                                nullptr, nullptr, nullptr, C_, C_, 4, 0);

    // ---- cross-attention ----
    ln_bf<<<BN_, 256, 0, stream>>>(out, ln2g, ln2b, hbz);
    dense_mfma<<<dim3(4, 64), 256, 0, stream>>>(hbz, ca_wqt, ca_bq, nullptr, nullptr,
                                                qbf, nullptr, nullptr, C_, C_, 0, 0);
    dense_mfma<<<dim3(2, 18), 256, 0, stream>>>(visbf, ca_wkvt, bkv_ca, nullptr, nullptr,
                                                kbf, vtbf, nullptr, 256, C_, 3, M_);
    attn_mfma<<<dim3(N_/64, B_*H_, 2), 256, 0, stream>>>(qbf, kbf, vtbf, opart, lpart, M_, 0);
    attn_combine<<<(BN_*C_)/1024, 256, 0, stream>>>(opart, lpart, obf, 2);
    dense_mfma<<<dim3(4, 64), 256, 0, stream>>>(obf, ca_wot, ca_bo, nullptr, out,
                                                nullptr, nullptr, nullptr, C_, C_, 1, 0);

    // ---- MoE ----
    ln_dual<<<BN_, 256, 0, stream>>>(out, ln3g, ln3b, hbuf, hbz);
    router_logits<<<BN_/4, 256, 0, stream>>>(hbuf, rw, rb, gprobs, topi, gatesv);
    router_reduce<<<16, 256, 0, stream>>>(gprobs, topi, ctrl, psum);
    router_scatter<<<BN_/256, 256, 0, stream>>>(topi, gatesv, rowtok, slotidx, ctrl);
    moe_mfma<<<dim3(F_/128, BN_/128, E_), 256, 0, stream>>>(
        hbz, w1t, e_b1, moeH, rowtok, ctrl, F_, C_, 1);
    moe_mfma<<<dim3(C_/128, BN_/128, E_), 256, 0, stream>>>(
        moeH, w2t, e_b2, eoslots, rowtok, ctrl, C_, F_, 2);
    moe_combine<<<(BN_*C_)/1024, 256, 0, stream>>>(eoslots, slotidx, gatesv, ctrl, psum, out);
}